// Round 6
// baseline (2476.255 us; speedup 1.0000x reference)
//
#include <hip/hip_runtime.h>
#include <math.h>

#define NB 64       // batch
#define NT 128      // time steps
#define NE 64       // embedding
#define NU 512      // units
#define NG 2048     // 4*U
#define NV 2000     // vocab
#define BU (NB*NU)
#define GRID_LSTM 256

typedef __attribute__((ext_vector_type(8))) short bf16x8;
typedef __attribute__((ext_vector_type(4))) float f32x4;
typedef __attribute__((ext_vector_type(8))) unsigned short u16x8;
typedef unsigned long long u64;

__device__ __forceinline__ unsigned short f2bf(float x) {
    unsigned int u = __float_as_uint(x);
    u += 0x7FFFu + ((u >> 16) & 1u);
    return (unsigned short)(u >> 16);
}

__device__ __forceinline__ float fsigmoid(float x) {
    return __builtin_amdgcn_rcpf(1.f + __expf(-x));
}
__device__ __forceinline__ float ftanh(float x) {
    return 1.f - 2.f * __builtin_amdgcn_rcpf(__expf(2.f * x) + 1.f);
}

// ---------------------------------------------------------------------------
// Cooperative LSTM, self-synchronizing via TAGGED h values.
// 256 blocks x 512 threads, 8 independent groups of 32 blocks (rg = bk&7 owns
// batch rows 8rg..8rg+7; cgi = bk>>3 owns units u0..u0+16). Wave wv owns
// k-slice [64wv,64wv+64). Wh register-resident.
//
// h exchange: each h value is published as ONE 64-bit relaxed agent-scope
// store {tag=t+1 (hi32) | fp32 bits (lo32)} into slot parity (t+1)&1.
// Consumers poll exactly their own slice; a matching tag means the payload
// in the same load is valid. This removes the producer vmcnt drain, the
// flag store round-trip, two of three barriers, and the separate h reload
// round-trip (3 serialized IF round-trips -> 1). Tag matching transitively
// implies the old barrier's guarantees (see analysis): one __syncthreads per
// step + parity-double-buffered psum is race-free, no ABA.
// Tag buffers MUST be zeroed each launch (workspace poison 0xAA would forge
// valid-looking future tags).
// ---------------------------------------------------------------------------
__global__ __launch_bounds__(512, 1)
void lstm_coop(const float* __restrict__ emb, const int* __restrict__ ids,
               const float* __restrict__ Wx, const float* __restrict__ Wh,
               const float* __restrict__ bias,
               const float* __restrict__ h0, const float* __restrict__ c0,
               float* __restrict__ Hout, u64* __restrict__ htag,
               float* __restrict__ hfin, float* __restrict__ cfin)
{
    __shared__ float psum[2][8][8][64];        // 32 KB, parity = t&1
    __shared__ float hlds[8][512];             // 16 KB

    const int tid  = threadIdx.x;
    const int wv   = tid >> 6;                 // 0..7 k-slice
    const int cl   = tid & 63;
    const int bk   = blockIdx.x;
    const int rg   = bk & 7;                   // group (8 groups x 32 blocks)
    const int cgi  = bk >> 3;                  // 0..31 unit slice
    const int brow0 = rg * 8;
    const int u0    = cgi * 16;
    const int gate  = cl >> 4;
    const int uu_c  = cl & 15;
    const int colg  = gate * 512 + u0 + uu_c;

    float w[64];
#pragma unroll
    for (int kk = 0; kk < 64; ++kk) w[kk] = Wh[(size_t)(wv * 64 + kk) * NG + colg];
    float wx[8];
#pragma unroll
    for (int ee = 0; ee < 8; ++ee) wx[ee] = Wx[(size_t)(wv * 8 + ee) * NG + colg];

    const int bl  = tid >> 4;                  // tid<128: row
    const int uug = tid & 15;
    float creg = 0.f;
    float b4[4] = {0.f, 0.f, 0.f, 0.f};
    if (tid < 128) {
#pragma unroll
        for (int g = 0; g < 4; ++g) b4[g] = bias[g * 512 + u0 + uug];
        if (c0) creg = c0[(brow0 + bl) * NU + u0 + uug];
    }

    const int col = wv * 64 + cl;              // this lane's h column

    for (int t = 0; t < NT; ++t) {
        // ---- acquire h_state(t) into own LDS cols (tag-poll = sync + load)
        if (t == 0) {
#pragma unroll
            for (int b = 0; b < 8; ++b)
                hlds[b][col] = h0 ? h0[(brow0 + b) * NU + col] : 0.f;
        } else {
            u64* slot = htag + (size_t)(t & 1) * BU + (size_t)brow0 * NU;
            u64 pv[8];
            while (true) {
                bool ok = true;
#pragma unroll
                for (int b = 0; b < 8; ++b) {
                    pv[b] = __hip_atomic_load(&slot[b * NU + col],
                                              __ATOMIC_RELAXED, __HIP_MEMORY_SCOPE_AGENT);
                    ok &= ((unsigned)(pv[b] >> 32) == (unsigned)t);
                }
                if (__all(ok)) break;
                __builtin_amdgcn_s_sleep(2);
            }
#pragma unroll
            for (int b = 0; b < 8; ++b)
                hlds[b][col] = __uint_as_float((unsigned)pv[b]);
        }

        // ---- z partial: own k-slice from hlds (broadcast LDS reads)
        float acc[8];
#pragma unroll
        for (int b = 0; b < 8; ++b) {
            const float4* hb4 = reinterpret_cast<const float4*>(&hlds[b][wv * 64]);
            float a0 = 0.f, a1 = 0.f, a2 = 0.f, a3 = 0.f;
#pragma unroll
            for (int k4 = 0; k4 < 16; k4 += 4) {
                float4 v0 = hb4[k4 + 0];
                a0 += v0.x * w[4 * k4 + 0] + v0.y * w[4 * k4 + 1] + v0.z * w[4 * k4 + 2] + v0.w * w[4 * k4 + 3];
                float4 v1 = hb4[k4 + 1];
                a1 += v1.x * w[4 * k4 + 4] + v1.y * w[4 * k4 + 5] + v1.z * w[4 * k4 + 6] + v1.w * w[4 * k4 + 7];
                float4 v2 = hb4[k4 + 2];
                a2 += v2.x * w[4 * k4 + 8] + v2.y * w[4 * k4 + 9] + v2.z * w[4 * k4 + 10] + v2.w * w[4 * k4 + 11];
                float4 v3 = hb4[k4 + 3];
                a3 += v3.x * w[4 * k4 + 12] + v3.y * w[4 * k4 + 13] + v3.z * w[4 * k4 + 14] + v3.w * w[4 * k4 + 15];
            }
            const int idb = ids[(brow0 + b) * NT + t];
            const float4* eb = reinterpret_cast<const float4*>(emb + (size_t)idb * NE + wv * 8);
            float4 e0 = eb[0], e1 = eb[1];
            a0 += e0.x * wx[0] + e0.y * wx[1] + e0.z * wx[2] + e0.w * wx[3];
            a1 += e1.x * wx[4] + e1.y * wx[5] + e1.z * wx[6] + e1.w * wx[7];
            acc[b] = (a0 + a1) + (a2 + a3);
        }
        const int par = t & 1;
#pragma unroll
        for (int b = 0; b < 8; ++b) psum[par][wv][b][cl] = acc[b];
        __syncthreads();                       // the ONLY barrier per step

        // ---- gates + state update + tagged publish
        if (tid < 128) {
            float z[4];
#pragma unroll
            for (int g = 0; g < 4; ++g) {
                float s = b4[g];
#pragma unroll
                for (int w8 = 0; w8 < 8; ++w8) s += psum[par][w8][bl][g * 16 + uug];
                z[g] = s;
            }
            const float i_ = fsigmoid(z[0]);
            const float f_ = fsigmoid(z[1]);
            const float g_ = ftanh(z[2]);
            const float o_ = fsigmoid(z[3]);
            creg = f_ * creg + i_ * g_;
            const float h_ = o_ * ftanh(creg);
            const int row = brow0 + bl;

            const u64 pkt = ((u64)(unsigned)(t + 1) << 32) | (u64)__float_as_uint(h_);
            __hip_atomic_store(&htag[(size_t)((t + 1) & 1) * BU + row * NU + u0 + uug],
                               pkt, __ATOMIC_RELAXED, __HIP_MEMORY_SCOPE_AGENT);
            Hout[((size_t)row * NT + t) * NU + u0 + uug] = h_;   // drains in background
            if (t == NT - 1) {
                hfin[row * NU + u0 + uug] = h_;                  // plain final h
                cfin[row * NU + u0 + uug] = creg;
            }
        }
    }
}

// ---------------------------------------------------------------------------
// Attention: one wave per (b,q), registers + butterflies.
// ---------------------------------------------------------------------------
__global__ __launch_bounds__(256)
void attn_kernel(const float* __restrict__ S, const float* __restrict__ Hbuf,
                 const float* __restrict__ s0, float* __restrict__ A)
{
    const int tid  = threadIdx.x;
    const int wv   = tid >> 6;
    const int lane = tid & 63;
    const int b    = blockIdx.x >> 5;
    const int q    = (blockIdx.x & 31) * 4 + wv;

    const float* qrow = (q == 0) ? (s0 + (size_t)b * NU)
                                 : (S + ((size_t)b * NT + (q - 1)) * NU);
    const float4* q4 = reinterpret_cast<const float4*>(qrow);
    const float4 qa = q4[lane], qb = q4[64 + lane];
    const float4* Hb = reinterpret_cast<const float4*>(Hbuf + (size_t)b * NT * NU);

    float sr0 = 0.f, sr1 = 0.f;
    for (int k = 0; k < NT; ++k) {
        const float4* hk = Hb + (size_t)k * 128;
        float4 ha = hk[lane], hc = hk[64 + lane];
        float d = qa.x * ha.x + qa.y * ha.y + qa.z * ha.z + qa.w * ha.w
                + qb.x * hc.x + qb.y * hc.y + qb.z * hc.z + qb.w * hc.w;
#pragma unroll
        for (int o = 32; o; o >>= 1) d += __shfl_xor(d, o);
        if ((k & 63) == lane) { if (k < 64) sr0 = d; else sr1 = d; }
        if ((k & 31) == 31) __syncthreads();
    }

    float m = fmaxf(sr0, sr1);
#pragma unroll
    for (int o = 32; o; o >>= 1) m = fmaxf(m, __shfl_xor(m, o));
    float e0 = expf(sr0 - m), e1 = expf(sr1 - m);
    float s = e0 + e1;
#pragma unroll
    for (int o = 32; o; o >>= 1) s += __shfl_xor(s, o);
    const float inv = 1.f / s;
    e0 *= inv; e1 *= inv;

    float4 acc0 = {0.f, 0.f, 0.f, 0.f}, acc1 = {0.f, 0.f, 0.f, 0.f};
    for (int k = 0; k < 64; ++k) {
        const float wk = __shfl(e0, k);
        const float4* hk = Hb + (size_t)k * 128;
        float4 ha = hk[lane], hc = hk[64 + lane];
        acc0.x += wk * ha.x; acc0.y += wk * ha.y; acc0.z += wk * ha.z; acc0.w += wk * ha.w;
        acc1.x += wk * hc.x; acc1.y += wk * hc.y; acc1.z += wk * hc.z; acc1.w += wk * hc.w;
        if ((k & 31) == 31) __syncthreads();
    }
    for (int k = 0; k < 64; ++k) {
        const float wk = __shfl(e1, k);
        const float4* hk = Hb + (size_t)(64 + k) * 128;
        float4 ha = hk[lane], hc = hk[64 + lane];
        acc0.x += wk * ha.x; acc0.y += wk * ha.y; acc0.z += wk * ha.z; acc0.w += wk * ha.w;
        acc1.x += wk * hc.x; acc1.y += wk * hc.y; acc1.z += wk * hc.z; acc1.w += wk * hc.w;
        if ((k & 31) == 31) __syncthreads();
    }
    float4* Aq = reinterpret_cast<float4*>(A + ((size_t)b * NT + q) * NU);
    Aq[lane] = acc0;
    Aq[64 + lane] = acc1;
}

// ---------------------------------------------------------------------------
// Convert yo=[S|A] (fp32) -> bf16 [8192][1024] (aliases Hbuf; runs after attn)
// ---------------------------------------------------------------------------
__global__ __launch_bounds__(256)
void conv_yo(const float* __restrict__ S, const float* __restrict__ A,
             unsigned short* __restrict__ yo)
{
    const int base = (blockIdx.x * 256 + threadIdx.x) * 8;
    const int row = base >> 10;
    const int col = base & 1023;
    const float* src = (col < 512) ? (S + (size_t)row * NU + col)
                                   : (A + (size_t)row * NU + (col - 512));
    const float4 v0 = reinterpret_cast<const float4*>(src)[0];
    const float4 v1 = reinterpret_cast<const float4*>(src)[1];
    u16x8 o;
    o[0] = f2bf(v0.x); o[1] = f2bf(v0.y); o[2] = f2bf(v0.z); o[3] = f2bf(v0.w);
    o[4] = f2bf(v1.x); o[5] = f2bf(v1.y); o[6] = f2bf(v1.z); o[7] = f2bf(v1.w);
    *reinterpret_cast<u16x8*>(yo + base) = o;
}

// ---------------------------------------------------------------------------
// Transpose dense_W [1024][2000] fp32 -> Wt [2048][1024] bf16 (pad rows zero)
// ---------------------------------------------------------------------------
__global__ __launch_bounds__(256)
void conv_Wt(const float* __restrict__ W, unsigned short* __restrict__ Wt)
{
    __shared__ float lt[64][65];
    const int tid = threadIdx.x;
    const int c0 = blockIdx.x * 64;
    const int k0 = blockIdx.y * 64;
#pragma unroll
    for (int j = 0; j < 16; ++j) {
        const int lin = tid + 256 * j;
        const int kk = lin >> 6, cc = lin & 63;
        const int c = c0 + cc;
        lt[cc][kk] = (c < NV) ? W[(size_t)(k0 + kk) * NV + c] : 0.f;
    }
    __syncthreads();
    const int c = tid >> 2, kseg = tid & 3;
    unsigned short tmp[16];
#pragma unroll
    for (int m = 0; m < 16; ++m)
        tmp[m] = f2bf(lt[c][kseg * 16 + m]);
    unsigned short* dst = Wt + (size_t)(c0 + c) * 1024 + k0 + kseg * 16;
    *reinterpret_cast<u16x8*>(dst)     = *reinterpret_cast<u16x8*>(tmp);
    *reinterpret_cast<u16x8*>(dst + 8) = *reinterpret_cast<u16x8*>(tmp + 8);
}

// ---------------------------------------------------------------------------
// Dense via bf16 MFMA: out[8192][2000] = yo[8192][1024] x W[1024][2000] + b.
// ---------------------------------------------------------------------------
__global__ __launch_bounds__(256)
void dense_mfma(const unsigned short* __restrict__ yo,
                const unsigned short* __restrict__ Wt,
                const float* __restrict__ bias, float* __restrict__ out)
{
    __shared__ unsigned short Asm[128][40];
    __shared__ unsigned short Bsm[128][40];
    const int tid  = threadIdx.x;
    const int wave = tid >> 6, lane = tid & 63;
    const int wm = wave >> 1, wn = wave & 1;
    const int r0 = blockIdx.y * 128, c0 = blockIdx.x * 128;
    const int rr = lane & 15, kh = lane >> 4;

    f32x4 acc[4][4];
#pragma unroll
    for (int m = 0; m < 4; ++m)
#pragma unroll
        for (int n = 0; n < 4; ++n) acc[m][n] = (f32x4){0.f, 0.f, 0.f, 0.f};

    for (int k0 = 0; k0 < 1024; k0 += 32) {
        __syncthreads();
#pragma unroll
        for (int h = 0; h < 2; ++h) {
            const int row = (tid >> 2) + h * 64, seg = tid & 3;
            *reinterpret_cast<uint4*>(&Asm[row][seg * 8]) =
                *reinterpret_cast<const uint4*>(yo + (size_t)(r0 + row) * 1024 + k0 + seg * 8);
            *reinterpret_cast<uint4*>(&Bsm[row][seg * 8]) =
                *reinterpret_cast<const uint4*>(Wt + (size_t)(c0 + row) * 1024 + k0 + seg * 8);
        }
        __syncthreads();
        bf16x8 af[4], bfr[4];
#pragma unroll
        for (int m = 0; m < 4; ++m)
            af[m] = *reinterpret_cast<const bf16x8*>(&Asm[wm * 64 + m * 16 + rr][kh * 8]);
#pragma unroll
        for (int n = 0; n < 4; ++n)
            bfr[n] = *reinterpret_cast<const bf16x8*>(&Bsm[wn * 64 + n * 16 + rr][kh * 8]);
#pragma unroll
        for (int m = 0; m < 4; ++m)
#pragma unroll
            for (int n = 0; n < 4; ++n)
                acc[m][n] = __builtin_amdgcn_mfma_f32_16x16x32_bf16(af[m], bfr[n], acc[m][n], 0, 0, 0);
    }

#pragma unroll
    for (int m = 0; m < 4; ++m) {
#pragma unroll
        for (int n = 0; n < 4; ++n) {
            const int c = c0 + wn * 64 + n * 16 + rr;
            if (c < NV) {
                const float bc = bias[c];
#pragma unroll
                for (int reg = 0; reg < 4; ++reg) {
                    const int r = r0 + wm * 64 + m * 16 + kh * 4 + reg;
                    out[(size_t)r * NV + c] = acc[m][n][reg] + bc;
                }
            }
        }
    }
}

// ---------------------------------------------------------------------------
// In-place row softmax over V=2000 logits.
// ---------------------------------------------------------------------------
__global__ __launch_bounds__(256)
void softmax_rows(float* __restrict__ out)
{
    __shared__ float red[4];
    const int t = threadIdx.x;
    float* row = out + (size_t)blockIdx.x * NV;

    float v[8];
    float m = -INFINITY;
#pragma unroll
    for (int i = 0; i < 8; ++i) {
        const int j = t + 256 * i;
        v[i] = (j < NV) ? row[j] : -INFINITY;
        m = fmaxf(m, v[i]);
    }
#pragma unroll
    for (int o = 32; o; o >>= 1) m = fmaxf(m, __shfl_xor(m, o));
    if ((t & 63) == 0) red[t >> 6] = m;
    __syncthreads();
    m = fmaxf(fmaxf(red[0], red[1]), fmaxf(red[2], red[3]));
    __syncthreads();

    float s = 0.f;
#pragma unroll
    for (int i = 0; i < 8; ++i) {
        const int j = t + 256 * i;
        if (j < NV) { v[i] = expf(v[i] - m); s += v[i]; }
    }
#pragma unroll
    for (int o = 32; o; o >>= 1) s += __shfl_xor(s, o);
    if ((t & 63) == 0) red[t >> 6] = s;
    __syncthreads();
    const float inv = 1.f / (red[0] + red[1] + red[2] + red[3]);
#pragma unroll
    for (int i = 0; i < 8; ++i) {
        const int j = t + 256 * i;
        if (j < NV) row[j] = v[i] * inv;
    }
}

// ---------------------------------------------------------------------------
extern "C" void kernel_launch(void* const* d_in, const int* in_sizes, int n_in,
                              void* d_out, int out_size, void* d_ws, size_t ws_size,
                              hipStream_t stream)
{
    const int*   x       = (const int*)  d_in[0];
    const int*   y       = (const int*)  d_in[1];
    const float* enc_emb = (const float*)d_in[2];
    const float* enc_Wx  = (const float*)d_in[3];
    const float* enc_Wh  = (const float*)d_in[4];
    const float* enc_b   = (const float*)d_in[5];
    const float* dec_emb = (const float*)d_in[6];
    const float* dec_Wx  = (const float*)d_in[7];
    const float* dec_Wh  = (const float*)d_in[8];
    const float* dec_b   = (const float*)d_in[9];
    const float* dns_W   = (const float*)d_in[10];
    const float* dns_b   = (const float*)d_in[11];
    float* out = (float*)d_out;

    float* ws   = (float*)d_ws;
    float* Hbuf = ws;                                  // [B,T,U] fp32 (aliased by yo bf16)
    float* Sbuf = Hbuf + (size_t)NB * NT * NU;
    float* Abuf = Sbuf + (size_t)NB * NT * NU;
    unsigned short* Wt = (unsigned short*)(Abuf + (size_t)NB * NT * NU);  // [2048][1024] bf16
    u64*  htag_e = (u64*)(Wt + (size_t)2048 * 1024);   // [2][BU] tagged h, encoder
    u64*  htag_d = htag_e + (size_t)2 * BU;            // [2][BU] tagged h, decoder
    float* hfin_e = (float*)(htag_d + (size_t)2 * BU); // enc final h (plain)
    float* hfin_d = hfin_e + BU;                       // dec final h (plain, unused)
    float* cfe  = hfin_d + BU;                         // enc final c
    float* cfd  = cfe + BU;                            // dec final c
    unsigned short* yo = (unsigned short*)Hbuf;        // bf16 [8192][1024], alias

    // tag buffers MUST be zeroed every call (0xAA poison would forge tags)
    hipMemsetAsync(htag_e, 0, (size_t)4 * BU * sizeof(u64), stream);

    // W transpose+convert first (independent of LSTMs)
    conv_Wt<<<dim3(32, 16), dim3(256), 0, stream>>>(dns_W, Wt);

    const float* nul = nullptr;
    {   // encoder LSTM
        void* args[] = { (void*)&enc_emb, (void*)&x, (void*)&enc_Wx, (void*)&enc_Wh,
                         (void*)&enc_b, (void*)&nul, (void*)&nul,
                         (void*)&Hbuf, (void*)&htag_e, (void*)&hfin_e, (void*)&cfe };
        (void)hipLaunchCooperativeKernel(reinterpret_cast<void*>(lstm_coop),
                                         dim3(GRID_LSTM), dim3(512), args, 0, stream);
    }
    {   // decoder LSTM: h0 = enc final h, c0 = enc final c
        const float* h0 = hfin_e;
        const float* c0 = cfe;
        void* args[] = { (void*)&dec_emb, (void*)&y, (void*)&dec_Wx, (void*)&dec_Wh,
                         (void*)&dec_b, (void*)&h0, (void*)&c0,
                         (void*)&Sbuf, (void*)&htag_d, (void*)&hfin_d, (void*)&cfd };
        (void)hipLaunchCooperativeKernel(reinterpret_cast<void*>(lstm_coop),
                                         dim3(GRID_LSTM), dim3(512), args, 0, stream);
    }
    attn_kernel<<<dim3(NB * 32), dim3(256), 0, stream>>>(Sbuf, Hbuf, hfin_e, Abuf);
    conv_yo<<<dim3(4096), dim3(256), 0, stream>>>(Sbuf, Abuf, yo);
    dense_mfma<<<dim3(16, 64), dim3(256), 0, stream>>>(yo, Wt, dns_b, out);
    softmax_rows<<<dim3(NB * NT), dim3(256), 0, stream>>>(out);
}

// Round 9
// 1255.695 us; speedup vs baseline: 1.9720x; 1.9720x over previous
//
#include <hip/hip_runtime.h>
#include <math.h>

#define NB 64       // batch
#define NT 128      // time steps
#define NE 64       // embedding
#define NU 512      // units
#define NG 2048     // 4*U
#define NV 2000     // vocab
#define BU (NB*NU)
#define GRID_LSTM 256
#define KTOT 576        // 512 (h) + 64 (emb) = 18 K-tiles of 32
#define HSTRIDE 580     // hlds row stride (floats): 16B-aligned, 2-way-bank-free
#define WSTRIDE 584     // whb row stride (shorts): 16B-aligned, conflict-benign
#define SMEM_BYTES (64*WSTRIDE*2 + 16*HSTRIDE*4 + 8*64*4)   // 74752+37120+2048 = 113920

typedef __attribute__((ext_vector_type(8))) short bf16x8;
typedef __attribute__((ext_vector_type(4))) float f32x4;
typedef __attribute__((ext_vector_type(8))) unsigned short u16x8;

__device__ __forceinline__ unsigned short f2bf(float x) {
    unsigned int u = __float_as_uint(x);
    u += 0x7FFFu + ((u >> 16) & 1u);
    return (unsigned short)(u >> 16);
}
__device__ __forceinline__ float fsigmoid(float x) {
    return __builtin_amdgcn_rcpf(1.f + __expf(-x));
}
__device__ __forceinline__ float ftanh(float x) {
    return 1.f - 2.f * __builtin_amdgcn_rcpf(__expf(2.f * x) + 1.f);
}

// ---------------------------------------------------------------------------
// Cooperative LSTM — R5's PROVEN sync protocol verbatim; compute engine
// swapped from fp32 GEMV to bf16 MFMA (fp32 h/c state, bf16 matmul inputs).
// 256 blocks x 512 threads, 8 groups x 32 blocks; rg=bk&7 owns rows 8rg..+8;
// cgi=bk>>3 owns units u0..u0+16 (64 z-cols = 4 gates x 16 units).
// A = [h(16-row padded, rows 8-15 zero) | emb_t], K=576. B = WhT slice (bf16,
// transposed [col][k]) staged once in LDS. 4 MFMA waves, one gate(16 cols)
// each, 18-tile K-chain; frag mappings identical to proven dense_mfma.
// ---------------------------------------------------------------------------
__global__ __launch_bounds__(512, 1)
void lstm_coop(const int* __restrict__ ids, const float* __restrict__ emb,
               const unsigned short* __restrict__ WhT,
               const float* __restrict__ bias,
               const float* __restrict__ h0, const float* __restrict__ c0,
               float* __restrict__ Hout, float* __restrict__ hping,
               float* __restrict__ cfin, unsigned int* __restrict__ flags)
{
    extern __shared__ char smem[];
    unsigned short* whb = (unsigned short*)smem;                 // [64][WSTRIDE]
    float* hlds = (float*)(smem + 64 * WSTRIDE * 2);             // [16][HSTRIDE]
    float* zbuf = (float*)(smem + 64 * WSTRIDE * 2 + 16 * HSTRIDE * 4);  // [8][64]

    const int tid  = threadIdx.x;
    const int wv   = tid >> 6;                 // wave
    const int cl   = tid & 63;                 // lane
    const int bk   = blockIdx.x;
    const int rg   = bk & 7;                   // group (8 groups x 32 blocks)
    const int cgi  = bk >> 3;                  // 0..31 unit slice
    const int brow0 = rg * 8;
    const int u0    = cgi * 16;

    // gate threads: tid<128 -> (row bl, unit uug)
    const int bl  = tid >> 4;                  // valid tid<128: 0..7
    const int uug = tid & 15;
    float creg = 0.f;
    float b4[4] = {0.f, 0.f, 0.f, 0.f};
    if (tid < 128) {
#pragma unroll
        for (int g = 0; g < 4; ++g) b4[g] = bias[g * 512 + u0 + uug];
        if (c0) creg = c0[(brow0 + bl) * NU + u0 + uug];
    }

    // ---- stage B (WhT slice -> LDS, once): col cp, k-chunk ch (72 shorts)
    {
        const int cp = tid >> 3, ch = tid & 7;
        const int cg = (cp >> 4) * 512 + u0 + (cp & 15);     // global z-col
        const uint4* src = reinterpret_cast<const uint4*>(WhT + (size_t)cg * KTOT + ch * 72);
        uint4* dst = reinterpret_cast<uint4*>(whb + cp * WSTRIDE + ch * 72);
#pragma unroll
        for (int i = 0; i < 9; ++i) dst[i] = src[i];
    }

    // ---- stage h(0) (own col slice), zero pad rows 8-15, stage emb(0)
    const int col = wv * 64 + cl;
#pragma unroll
    for (int b = 0; b < 8; ++b)
        hlds[b * HSTRIDE + col] = h0 ? h0[(brow0 + b) * NU + col] : 0.f;
    for (int i = tid; i < 8 * HSTRIDE; i += 512) hlds[8 * HSTRIDE + i] = 0.f;
    {
        const int idb = ids[(brow0 + wv) * NT + 0];
        hlds[wv * HSTRIDE + 512 + cl] = emb[(size_t)idb * NE + cl];
    }
    unsigned int* fl = flags + rg * 64;

    for (int t = 0; t < NT; ++t) {
        __syncthreads();                       // B#0: hlds + whb visible to all

        // ---- z = [h|emb] @ [Wh;Wx] via MFMA: wave wv<4 handles gate wv
        if (wv < 4) {
            const int rr = cl & 15, kh = cl >> 4;
            f32x4 acc = {0.f, 0.f, 0.f, 0.f};
            const float* arow = hlds + rr * HSTRIDE;
            const unsigned short* brow = whb + (wv * 16 + rr) * WSTRIDE;
#pragma unroll
            for (int kt = 0; kt < 18; ++kt) {
                const int kb = kt * 32 + kh * 8;
                float4 a0 = *reinterpret_cast<const float4*>(arow + kb);
                float4 a1 = *reinterpret_cast<const float4*>(arow + kb + 4);
                bf16x8 af;
                af[0] = (short)f2bf(a0.x); af[1] = (short)f2bf(a0.y);
                af[2] = (short)f2bf(a0.z); af[3] = (short)f2bf(a0.w);
                af[4] = (short)f2bf(a1.x); af[5] = (short)f2bf(a1.y);
                af[6] = (short)f2bf(a1.z); af[7] = (short)f2bf(a1.w);
                bf16x8 bf = *reinterpret_cast<const bf16x8*>(brow + kb);
                acc = __builtin_amdgcn_mfma_f32_16x16x32_bf16(af, bf, acc, 0, 0, 0);
            }
            if (cl < 32) {                     // rows 0-7 real (8-15 = pad)
#pragma unroll
                for (int reg = 0; reg < 4; ++reg)
                    zbuf[(kh * 4 + reg) * 64 + wv * 16 + rr] = acc[reg];
            }
        }
        __syncthreads();                       // B#1: zbuf complete

        // ---- gates + state update + h publish (EXACT R5 protocol)
        float h_ = 0.f;
        if (tid < 128) {
            float z[4];
#pragma unroll
            for (int g = 0; g < 4; ++g) z[g] = b4[g] + zbuf[bl * 64 + g * 16 + uug];
            const float i_ = fsigmoid(z[0]);
            const float f_ = fsigmoid(z[1]);
            const float g_ = ftanh(z[2]);
            const float o_ = fsigmoid(z[3]);
            creg = f_ * creg + i_ * g_;
            h_ = o_ * ftanh(creg);
            float* hw = hping + ((t + 1) & 1) * BU;
            __hip_atomic_store(&hw[(brow0 + bl) * NU + u0 + uug], h_,
                               __ATOMIC_RELAXED, __HIP_MEMORY_SCOPE_AGENT);
        }
        if (t == NT - 1) {
            if (tid < 128)
                Hout[((size_t)(brow0 + bl) * NT + t) * NU + u0 + uug] = h_;
            break;                             // final h/c flushed at kernel end
        }

        if (tid < 128)
            asm volatile("s_waitcnt vmcnt(0)" ::: "memory");  // h at coherence pt
        __syncthreads();                       // B#2: all h stores complete

        if (tid < 128 && (tid & 63) == 0)
            __hip_atomic_store(&fl[(tid >> 6) * 32 + cgi], (unsigned)(t + 1),
                               __ATOMIC_RELAXED, __HIP_MEMORY_SCOPE_AGENT);
        if (tid < 128)                         // off critical path: drains in bg
            Hout[((size_t)(brow0 + bl) * NT + t) * NU + u0 + uug] = h_;

        if (wv == 0) {                         // single polling wave per block
            const unsigned target = (unsigned)(t + 1);
            while (true) {
                unsigned v = __hip_atomic_load(&fl[cl], __ATOMIC_RELAXED,
                                               __HIP_MEMORY_SCOPE_AGENT);
#pragma unroll
                for (int o = 16; o; o >>= 1) {
                    unsigned v2 = (unsigned)__shfl_xor((int)v, o);
                    v = v2 < v ? v2 : v;
                }
                if (v >= target) break;
                __builtin_amdgcn_s_sleep(1);
            }
        }
        __syncthreads();                       // B#3: release all waves

        // ---- reload own h slice + stage emb(t+1)
        {
            const float* hr = hping + ((t + 1) & 1) * BU + (size_t)brow0 * NU;
            float tmp[8];
#pragma unroll
            for (int b = 0; b < 8; ++b)
                tmp[b] = __hip_atomic_load(const_cast<float*>(&hr[b * NU + col]),
                                           __ATOMIC_RELAXED, __HIP_MEMORY_SCOPE_AGENT);
#pragma unroll
            for (int b = 0; b < 8; ++b) hlds[b * HSTRIDE + col] = tmp[b];
            const int idb = ids[(brow0 + wv) * NT + (t + 1)];
            hlds[wv * HSTRIDE + 512 + cl] = emb[(size_t)idb * NE + cl];
        }
    }
    if (tid < 128) cfin[(brow0 + bl) * NU + u0 + uug] = creg;
}

// ---------------------------------------------------------------------------
// WhT[c][k] = bf16( k<512 ? Wh[k][c] : Wx[k-512][c] ), c<2048, k<576.
// 64x64 transpose tiles via LDS; grid (2048/64, 576/64)=(32,9).
// ---------------------------------------------------------------------------
__global__ __launch_bounds__(256)
void conv_WhT(const float* __restrict__ Wh, const float* __restrict__ Wx,
              unsigned short* __restrict__ WhT)
{
    __shared__ float lt[64][65];
    const int tid = threadIdx.x;
    const int c0 = blockIdx.x * 64;
    const int k0 = blockIdx.y * 64;
#pragma unroll
    for (int j = 0; j < 16; ++j) {
        const int lin = tid + 256 * j;
        const int kk = lin >> 6, cc = lin & 63;
        const int k = k0 + kk;
        lt[cc][kk] = (k < 512) ? Wh[(size_t)k * NG + c0 + cc]
                               : Wx[(size_t)(k - 512) * NG + c0 + cc];
    }
    __syncthreads();
    const int c = tid >> 2, kseg = tid & 3;
    unsigned short tmp[16];
#pragma unroll
    for (int m = 0; m < 16; ++m)
        tmp[m] = f2bf(lt[c][kseg * 16 + m]);
    unsigned short* dst = WhT + (size_t)(c0 + c) * KTOT + k0 + kseg * 16;
    *reinterpret_cast<u16x8*>(dst)     = *reinterpret_cast<u16x8*>(tmp);
    *reinterpret_cast<u16x8*>(dst + 8) = *reinterpret_cast<u16x8*>(tmp + 8);
}

// ---------------------------------------------------------------------------
// Attention: one wave per (b,q), registers + butterflies.
// ---------------------------------------------------------------------------
__global__ __launch_bounds__(256)
void attn_kernel(const float* __restrict__ S, const float* __restrict__ Hbuf,
                 const float* __restrict__ s0, float* __restrict__ A)
{
    const int tid  = threadIdx.x;
    const int wv   = tid >> 6;
    const int lane = tid & 63;
    const int b    = blockIdx.x >> 5;
    const int q    = (blockIdx.x & 31) * 4 + wv;

    const float* qrow = (q == 0) ? (s0 + (size_t)b * NU)
                                 : (S + ((size_t)b * NT + (q - 1)) * NU);
    const float4* q4 = reinterpret_cast<const float4*>(qrow);
    const float4 qa = q4[lane], qb = q4[64 + lane];
    const float4* Hb = reinterpret_cast<const float4*>(Hbuf + (size_t)b * NT * NU);

    float sr0 = 0.f, sr1 = 0.f;
    for (int k = 0; k < NT; ++k) {
        const float4* hk = Hb + (size_t)k * 128;
        float4 ha = hk[lane], hc = hk[64 + lane];
        float d = qa.x * ha.x + qa.y * ha.y + qa.z * ha.z + qa.w * ha.w
                + qb.x * hc.x + qb.y * hc.y + qb.z * hc.z + qb.w * hc.w;
#pragma unroll
        for (int o = 32; o; o >>= 1) d += __shfl_xor(d, o);
        if ((k & 63) == lane) { if (k < 64) sr0 = d; else sr1 = d; }
        if ((k & 31) == 31) __syncthreads();
    }

    float m = fmaxf(sr0, sr1);
#pragma unroll
    for (int o = 32; o; o >>= 1) m = fmaxf(m, __shfl_xor(m, o));
    float e0 = expf(sr0 - m), e1 = expf(sr1 - m);
    float s = e0 + e1;
#pragma unroll
    for (int o = 32; o; o >>= 1) s += __shfl_xor(s, o);
    const float inv = 1.f / s;
    e0 *= inv; e1 *= inv;

    float4 acc0 = {0.f, 0.f, 0.f, 0.f}, acc1 = {0.f, 0.f, 0.f, 0.f};
    for (int k = 0; k < 64; ++k) {
        const float wk = __shfl(e0, k);
        const float4* hk = Hb + (size_t)k * 128;
        float4 ha = hk[lane], hc = hk[64 + lane];
        acc0.x += wk * ha.x; acc0.y += wk * ha.y; acc0.z += wk * ha.z; acc0.w += wk * ha.w;
        acc1.x += wk * hc.x; acc1.y += wk * hc.y; acc1.z += wk * hc.z; acc1.w += wk * hc.w;
        if ((k & 31) == 31) __syncthreads();
    }
    for (int k = 0; k < 64; ++k) {
        const float wk = __shfl(e1, k);
        const float4* hk = Hb + (size_t)(64 + k) * 128;
        float4 ha = hk[lane], hc = hk[64 + lane];
        acc0.x += wk * ha.x; acc0.y += wk * ha.y; acc0.z += wk * ha.z; acc0.w += wk * ha.w;
        acc1.x += wk * hc.x; acc1.y += wk * hc.y; acc1.z += wk * hc.z; acc1.w += wk * hc.w;
        if ((k & 31) == 31) __syncthreads();
    }
    float4* Aq = reinterpret_cast<float4*>(A + ((size_t)b * NT + q) * NU);
    Aq[lane] = acc0;
    Aq[64 + lane] = acc1;
}

// ---------------------------------------------------------------------------
// Convert yo=[S|A] (fp32) -> bf16 [8192][1024] (aliases Hbuf; runs after attn)
// ---------------------------------------------------------------------------
__global__ __launch_bounds__(256)
void conv_yo(const float* __restrict__ S, const float* __restrict__ A,
             unsigned short* __restrict__ yo)
{
    const int base = (blockIdx.x * 256 + threadIdx.x) * 8;
    const int row = base >> 10;
    const int col = base & 1023;
    const float* src = (col < 512) ? (S + (size_t)row * NU + col)
                                   : (A + (size_t)row * NU + (col - 512));
    const float4 v0 = reinterpret_cast<const float4*>(src)[0];
    const float4 v1 = reinterpret_cast<const float4*>(src)[1];
    u16x8 o;
    o[0] = f2bf(v0.x); o[1] = f2bf(v0.y); o[2] = f2bf(v0.z); o[3] = f2bf(v0.w);
    o[4] = f2bf(v1.x); o[5] = f2bf(v1.y); o[6] = f2bf(v1.z); o[7] = f2bf(v1.w);
    *reinterpret_cast<u16x8*>(yo + base) = o;
}

// ---------------------------------------------------------------------------
// Transpose dense_W [1024][2000] fp32 -> Wt [2048][1024] bf16 (pad rows zero)
// ---------------------------------------------------------------------------
__global__ __launch_bounds__(256)
void conv_Wt(const float* __restrict__ W, unsigned short* __restrict__ Wt)
{
    __shared__ float lt[64][65];
    const int tid = threadIdx.x;
    const int c0 = blockIdx.x * 64;
    const int k0 = blockIdx.y * 64;
#pragma unroll
    for (int j = 0; j < 16; ++j) {
        const int lin = tid + 256 * j;
        const int kk = lin >> 6, cc = lin & 63;
        const int c = c0 + cc;
        lt[cc][kk] = (c < NV) ? W[(size_t)(k0 + kk) * NV + c] : 0.f;
    }
    __syncthreads();
    const int c = tid >> 2, kseg = tid & 3;
    unsigned short tmp[16];
#pragma unroll
    for (int m = 0; m < 16; ++m)
        tmp[m] = f2bf(lt[c][kseg * 16 + m]);
    unsigned short* dst = Wt + (size_t)(c0 + c) * 1024 + k0 + kseg * 16;
    *reinterpret_cast<u16x8*>(dst)     = *reinterpret_cast<u16x8*>(tmp);
    *reinterpret_cast<u16x8*>(dst + 8) = *reinterpret_cast<u16x8*>(tmp + 8);
}

// ---------------------------------------------------------------------------
// Dense via bf16 MFMA: out[8192][2000] = yo[8192][1024] x W[1024][2000] + b.
// ---------------------------------------------------------------------------
__global__ __launch_bounds__(256)
void dense_mfma(const unsigned short* __restrict__ yo,
                const unsigned short* __restrict__ Wt,
                const float* __restrict__ bias, float* __restrict__ out)
{
    __shared__ unsigned short Asm[128][40];
    __shared__ unsigned short Bsm[128][40];
    const int tid  = threadIdx.x;
    const int wave = tid >> 6, lane = tid & 63;
    const int wm = wave >> 1, wn = wave & 1;
    const int r0 = blockIdx.y * 128, c0 = blockIdx.x * 128;
    const int rr = lane & 15, kh = lane >> 4;

    f32x4 acc[4][4];
#pragma unroll
    for (int m = 0; m < 4; ++m)
#pragma unroll
        for (int n = 0; n < 4; ++n) acc[m][n] = (f32x4){0.f, 0.f, 0.f, 0.f};

    for (int k0 = 0; k0 < 1024; k0 += 32) {
        __syncthreads();
#pragma unroll
        for (int h = 0; h < 2; ++h) {
            const int row = (tid >> 2) + h * 64, seg = tid & 3;
            *reinterpret_cast<uint4*>(&Asm[row][seg * 8]) =
                *reinterpret_cast<const uint4*>(yo + (size_t)(r0 + row) * 1024 + k0 + seg * 8);
            *reinterpret_cast<uint4*>(&Bsm[row][seg * 8]) =
                *reinterpret_cast<const uint4*>(Wt + (size_t)(c0 + row) * 1024 + k0 + seg * 8);
        }
        __syncthreads();
        bf16x8 af[4], bfr[4];
#pragma unroll
        for (int m = 0; m < 4; ++m)
            af[m] = *reinterpret_cast<const bf16x8*>(&Asm[wm * 64 + m * 16 + rr][kh * 8]);
#pragma unroll
        for (int n = 0; n < 4; ++n)
            bfr[n] = *reinterpret_cast<const bf16x8*>(&Bsm[wn * 64 + n * 16 + rr][kh * 8]);
#pragma unroll
        for (int m = 0; m < 4; ++m)
#pragma unroll
            for (int n = 0; n < 4; ++n)
                acc[m][n] = __builtin_amdgcn_mfma_f32_16x16x32_bf16(af[m], bfr[n], acc[m][n], 0, 0, 0);
    }

#pragma unroll
    for (int m = 0; m < 4; ++m) {
#pragma unroll
        for (int n = 0; n < 4; ++n) {
            const int c = c0 + wn * 64 + n * 16 + rr;
            if (c < NV) {
                const float bc = bias[c];
#pragma unroll
                for (int reg = 0; reg < 4; ++reg) {
                    const int r = r0 + wm * 64 + m * 16 + kh * 4 + reg;
                    out[(size_t)r * NV + c] = acc[m][n][reg] + bc;
                }
            }
        }
    }
}

// ---------------------------------------------------------------------------
// In-place row softmax over V=2000 logits.
// ---------------------------------------------------------------------------
__global__ __launch_bounds__(256)
void softmax_rows(float* __restrict__ out)
{
    __shared__ float red[4];
    const int t = threadIdx.x;
    float* row = out + (size_t)blockIdx.x * NV;

    float v[8];
    float m = -INFINITY;
#pragma unroll
    for (int i = 0; i < 8; ++i) {
        const int j = t + 256 * i;
        v[i] = (j < NV) ? row[j] : -INFINITY;
        m = fmaxf(m, v[i]);
    }
#pragma unroll
    for (int o = 32; o; o >>= 1) m = fmaxf(m, __shfl_xor(m, o));
    if ((t & 63) == 0) red[t >> 6] = m;
    __syncthreads();
    m = fmaxf(fmaxf(red[0], red[1]), fmaxf(red[2], red[3]));
    __syncthreads();

    float s = 0.f;
#pragma unroll
    for (int i = 0; i < 8; ++i) {
        const int j = t + 256 * i;
        if (j < NV) { v[i] = expf(v[i] - m); s += v[i]; }
    }
#pragma unroll
    for (int o = 32; o; o >>= 1) s += __shfl_xor(s, o);
    if ((t & 63) == 0) red[t >> 6] = s;
    __syncthreads();
    const float inv = 1.f / (red[0] + red[1] + red[2] + red[3]);
#pragma unroll
    for (int i = 0; i < 8; ++i) {
        const int j = t + 256 * i;
        if (j < NV) row[j] = v[i] * inv;
    }
}

// ---------------------------------------------------------------------------
extern "C" void kernel_launch(void* const* d_in, const int* in_sizes, int n_in,
                              void* d_out, int out_size, void* d_ws, size_t ws_size,
                              hipStream_t stream)
{
    const int*   x       = (const int*)  d_in[0];
    const int*   y       = (const int*)  d_in[1];
    const float* enc_emb = (const float*)d_in[2];
    const float* enc_Wx  = (const float*)d_in[3];
    const float* enc_Wh  = (const float*)d_in[4];
    const float* enc_b   = (const float*)d_in[5];
    const float* dec_emb = (const float*)d_in[6];
    const float* dec_Wx  = (const float*)d_in[7];
    const float* dec_Wh  = (const float*)d_in[8];
    const float* dec_b   = (const float*)d_in[9];
    const float* dns_W   = (const float*)d_in[10];
    const float* dns_b   = (const float*)d_in[11];
    float* out = (float*)d_out;

    float* ws   = (float*)d_ws;
    float* Hbuf = ws;                                  // [B,T,U] fp32 (aliased by yo bf16)
    float* Sbuf = Hbuf + (size_t)NB * NT * NU;
    float* Abuf = Sbuf + (size_t)NB * NT * NU;
    unsigned short* Wt = (unsigned short*)(Abuf + (size_t)NB * NT * NU);  // [2048][1024] bf16
    float* ehp  = (float*)(Wt + (size_t)2048 * 1024);  // enc h ping-pong [2][B,U]
    float* dhp  = ehp + 2 * BU;
    float* cfe  = dhp + 2 * BU;
    float* cfd  = cfe + BU;
    unsigned int* bar0 = (unsigned int*)(cfd + BU);    // 512 flags enc
    unsigned int* bar1 = bar0 + 512;                   // 512 flags dec
    unsigned short* WhT_e = (unsigned short*)(bar1 + 512);          // [2048][576] bf16
    unsigned short* WhT_d = WhT_e + (size_t)2048 * KTOT;            // [2048][576] bf16
    unsigned short* yo = (unsigned short*)Hbuf;        // bf16 [8192][1024], alias

    // flags MUST be zeroed every call (0xAA poison would forge future values)
    hipMemsetAsync(bar0, 0, 2 * 512 * sizeof(unsigned int), stream);

    // allow 111KB dynamic LDS for the LSTM kernel (idempotent host call)
    (void)hipFuncSetAttribute(reinterpret_cast<const void*>(lstm_coop),
                              hipFuncAttributeMaxDynamicSharedMemorySize, SMEM_BYTES);

    // weight conversions (independent of LSTMs)
    conv_WhT<<<dim3(32, 9), dim3(256), 0, stream>>>(enc_Wh, enc_Wx, WhT_e);
    conv_WhT<<<dim3(32, 9), dim3(256), 0, stream>>>(dec_Wh, dec_Wx, WhT_d);
    conv_Wt<<<dim3(32, 16), dim3(256), 0, stream>>>(dns_W, Wt);

    const float* nul = nullptr;
    {   // encoder LSTM
        void* args[] = { (void*)&x, (void*)&enc_emb, (void*)&WhT_e, (void*)&enc_b,
                         (void*)&nul, (void*)&nul,
                         (void*)&Hbuf, (void*)&ehp, (void*)&cfe, (void*)&bar0 };
        (void)hipLaunchCooperativeKernel(reinterpret_cast<void*>(lstm_coop),
                                         dim3(GRID_LSTM), dim3(512), args,
                                         SMEM_BYTES, stream);
    }
    {   // decoder LSTM: h0 = enc final h (ehp slot 0), c0 = enc final c
        const float* h0 = ehp;
        const float* c0 = cfe;
        void* args[] = { (void*)&y, (void*)&dec_emb, (void*)&WhT_d, (void*)&dec_b,
                         (void*)&h0, (void*)&c0,
                         (void*)&Sbuf, (void*)&dhp, (void*)&cfd, (void*)&bar1 };
        (void)hipLaunchCooperativeKernel(reinterpret_cast<void*>(lstm_coop),
                                         dim3(GRID_LSTM), dim3(512), args,
                                         SMEM_BYTES, stream);
    }
    attn_kernel<<<dim3(NB * 32), dim3(256), 0, stream>>>(Sbuf, Hbuf, ehp, Abuf);
    conv_yo<<<dim3(4096), dim3(256), 0, stream>>>(Sbuf, Abuf, yo);
    dense_mfma<<<dim3(16, 64), dim3(256), 0, stream>>>(yo, Wt, dns_b, out);
    softmax_rows<<<dim3(NB * NT), dim3(256), 0, stream>>>(out);
}

// Round 10
// 998.458 us; speedup vs baseline: 2.4801x; 1.2576x over previous
//
#include <hip/hip_runtime.h>
#include <math.h>

#define NB 64       // batch
#define NT 128      // time steps
#define NE 64       // embedding
#define NU 512      // units
#define NG 2048     // 4*U
#define NV 2000     // vocab
#define BU (NB*NU)
#define GRID_LSTM 256
#define KTOT 576        // 512 (h) + 64 (emb) = 18 K-tiles of 32
#define HS 584          // hlds row stride (shorts, 16B-aligned rows)
#define WSTRIDE 584     // whb row stride (shorts)
#define SMEM_BYTES (64*WSTRIDE*2 + 16*HS*2 + 2*8*64*4)   // 74752+18688+4096 = 97536

typedef __attribute__((ext_vector_type(8))) short bf16x8;
typedef __attribute__((ext_vector_type(4))) float f32x4;
typedef __attribute__((ext_vector_type(8))) unsigned short u16x8;

__device__ __forceinline__ unsigned short f2bf(float x) {
    unsigned int u = __float_as_uint(x);
    u += 0x7FFFu + ((u >> 16) & 1u);
    return (unsigned short)(u >> 16);
}
__device__ __forceinline__ float fsigmoid(float x) {
    return __builtin_amdgcn_rcpf(1.f + __expf(-x));
}
__device__ __forceinline__ float ftanh(float x) {
    return 1.f - 2.f * __builtin_amdgcn_rcpf(__expf(2.f * x) + 1.f);
}

// ---------------------------------------------------------------------------
// Cooperative LSTM — R5/R9's PROVEN sync protocol verbatim. Compute engine:
// bf16 MFMA with bf16 LDS operands (h exchanged fp32, converted at reload;
// emb pre-converted). 8 MFMA waves: wave wv = (gate wv&3, K-half wv>>2),
// 9 K-tiles each, partials in zbuf[2], gates sum both halves.
// 256 blocks x 512 threads, 8 groups x 32 blocks; rg=bk&7 owns rows 8rg..+8;
// cgi=bk>>3 owns units u0..u0+16 (64 z-cols = 4 gates x 16 units).
// ---------------------------------------------------------------------------
__global__ __launch_bounds__(512, 1)
void lstm_coop(const int* __restrict__ ids, const unsigned short* __restrict__ embb,
               const unsigned short* __restrict__ WhT,
               const float* __restrict__ bias,
               const float* __restrict__ h0, const float* __restrict__ c0,
               float* __restrict__ Hout, float* __restrict__ hping,
               float* __restrict__ cfin, unsigned int* __restrict__ flags)
{
    extern __shared__ char smem[];
    unsigned short* whb  = (unsigned short*)smem;                    // [64][WSTRIDE]
    unsigned short* hlds = (unsigned short*)(smem + 64 * WSTRIDE * 2); // [16][HS] bf16
    float* zbuf = (float*)(smem + 64 * WSTRIDE * 2 + 16 * HS * 2);   // [2][8][64]

    const int tid  = threadIdx.x;
    const int wv   = tid >> 6;                 // wave
    const int cl   = tid & 63;                 // lane
    const int bk   = blockIdx.x;
    const int rg   = bk & 7;                   // group (8 groups x 32 blocks)
    const int cgi  = bk >> 3;                  // 0..31 unit slice
    const int brow0 = rg * 8;
    const int u0    = cgi * 16;

    // gate threads: tid<128 -> (row bl, unit uug)
    const int bl  = tid >> 4;                  // valid tid<128: 0..7
    const int uug = tid & 15;
    float creg = 0.f;
    float b4[4] = {0.f, 0.f, 0.f, 0.f};
    if (tid < 128) {
#pragma unroll
        for (int g = 0; g < 4; ++g) b4[g] = bias[g * 512 + u0 + uug];
        if (c0) creg = c0[(brow0 + bl) * NU + u0 + uug];
    }

    // ---- stage B (WhT slice -> LDS, once): col cp, k-chunk ch (72 shorts)
    {
        const int cp = tid >> 3, ch = tid & 7;
        const int cg = (cp >> 4) * 512 + u0 + (cp & 15);     // global z-col
        const uint4* src = reinterpret_cast<const uint4*>(WhT + (size_t)cg * KTOT + ch * 72);
        uint4* dst = reinterpret_cast<uint4*>(whb + cp * WSTRIDE + ch * 72);
#pragma unroll
        for (int i = 0; i < 9; ++i) dst[i] = src[i];
    }

    // ---- stage h(0) bf16 (own col slice), zero pad rows 8-15, stage emb(0)
    const int col = wv * 64 + cl;
#pragma unroll
    for (int b = 0; b < 8; ++b)
        hlds[b * HS + col] = h0 ? f2bf(h0[(brow0 + b) * NU + col]) : (unsigned short)0;
    for (int i = tid; i < 8 * HS; i += 512) hlds[8 * HS + i] = 0;
    {
        const int idb = ids[(brow0 + wv) * NT + 0];
        hlds[wv * HS + 512 + cl] = embb[(size_t)idb * NE + cl];
    }
    unsigned int* fl = flags + rg * 64;

    for (int t = 0; t < NT; ++t) {
        __syncthreads();                       // B#0: hlds + whb visible to all

        // ---- z = [h|emb] @ [Wh;Wx] via MFMA: wave = (gate wv&3, K-half wv>>2)
        {
            const int g = wv & 3, half = wv >> 2;
            const int rr = cl & 15, kh = cl >> 4;
            f32x4 acc = {0.f, 0.f, 0.f, 0.f};
            const unsigned short* arow = hlds + rr * HS;
            const unsigned short* brow = whb + (g * 16 + rr) * WSTRIDE;
#pragma unroll
            for (int kt = 0; kt < 9; ++kt) {
                const int kb = (half * 9 + kt) * 32 + kh * 8;
                bf16x8 af = *reinterpret_cast<const bf16x8*>(arow + kb);
                bf16x8 bf = *reinterpret_cast<const bf16x8*>(brow + kb);
                acc = __builtin_amdgcn_mfma_f32_16x16x32_bf16(af, bf, acc, 0, 0, 0);
            }
            if (cl < 32) {                     // rows 0-7 real (8-15 = pad)
#pragma unroll
                for (int reg = 0; reg < 4; ++reg)
                    zbuf[half * 512 + (kh * 4 + reg) * 64 + g * 16 + rr] = acc[reg];
            }
        }
        __syncthreads();                       // B#1: zbuf complete

        // ---- gates + state update + h publish (EXACT R5 protocol)
        float h_ = 0.f;
        if (tid < 128) {
            float z[4];
#pragma unroll
            for (int g = 0; g < 4; ++g)
                z[g] = b4[g] + zbuf[bl * 64 + g * 16 + uug]
                             + zbuf[512 + bl * 64 + g * 16 + uug];
            const float i_ = fsigmoid(z[0]);
            const float f_ = fsigmoid(z[1]);
            const float g_ = ftanh(z[2]);
            const float o_ = fsigmoid(z[3]);
            creg = f_ * creg + i_ * g_;
            h_ = o_ * ftanh(creg);
            float* hw = hping + ((t + 1) & 1) * BU;
            __hip_atomic_store(&hw[(brow0 + bl) * NU + u0 + uug], h_,
                               __ATOMIC_RELAXED, __HIP_MEMORY_SCOPE_AGENT);
        }
        if (t == NT - 1) {
            if (tid < 128)
                Hout[((size_t)(brow0 + bl) * NT + t) * NU + u0 + uug] = h_;
            break;                             // final h/c flushed at kernel end
        }

        if (tid < 128)
            asm volatile("s_waitcnt vmcnt(0)" ::: "memory");  // h at coherence pt
        __syncthreads();                       // B#2: all h stores complete

        if (tid < 128 && (tid & 63) == 0)
            __hip_atomic_store(&fl[(tid >> 6) * 32 + cgi], (unsigned)(t + 1),
                               __ATOMIC_RELAXED, __HIP_MEMORY_SCOPE_AGENT);
        if (tid < 128)                         // off critical path: drains in bg
            Hout[((size_t)(brow0 + bl) * NT + t) * NU + u0 + uug] = h_;

        // ---- stage emb(t+1) (independent of h(t+1): hides in poll window)
        {
            const int idb = ids[(brow0 + wv) * NT + (t + 1)];
            hlds[wv * HS + 512 + cl] = embb[(size_t)idb * NE + cl];
        }

        if (wv == 0) {                         // single polling wave per block
            const unsigned target = (unsigned)(t + 1);
            while (true) {
                unsigned v = __hip_atomic_load(&fl[cl], __ATOMIC_RELAXED,
                                               __HIP_MEMORY_SCOPE_AGENT);
#pragma unroll
                for (int o = 16; o; o >>= 1) {
                    unsigned v2 = (unsigned)__shfl_xor((int)v, o);
                    v = v2 < v ? v2 : v;
                }
                if (v >= target) break;
                __builtin_amdgcn_s_sleep(1);
            }
        }
        __syncthreads();                       // B#3: release all waves

        // ---- reload own h slice fp32 (proven), convert to bf16 into LDS
        {
            const float* hr = hping + ((t + 1) & 1) * BU + (size_t)brow0 * NU;
            float tmp[8];
#pragma unroll
            for (int b = 0; b < 8; ++b)
                tmp[b] = __hip_atomic_load(const_cast<float*>(&hr[b * NU + col]),
                                           __ATOMIC_RELAXED, __HIP_MEMORY_SCOPE_AGENT);
#pragma unroll
            for (int b = 0; b < 8; ++b) hlds[b * HS + col] = f2bf(tmp[b]);
        }
    }
    if (tid < 128) cfin[(brow0 + bl) * NU + u0 + uug] = creg;
}

// ---------------------------------------------------------------------------
// emb table fp32 -> bf16 (one-time). n = VOCAB*NE elements.
// ---------------------------------------------------------------------------
__global__ __launch_bounds__(256)
void conv_emb(const float* __restrict__ e, unsigned short* __restrict__ o, int n)
{
    const int i = (blockIdx.x * 256 + threadIdx.x) * 8;
    if (i >= n) return;
    const float4 v0 = reinterpret_cast<const float4*>(e + i)[0];
    const float4 v1 = reinterpret_cast<const float4*>(e + i)[1];
    u16x8 r;
    r[0] = f2bf(v0.x); r[1] = f2bf(v0.y); r[2] = f2bf(v0.z); r[3] = f2bf(v0.w);
    r[4] = f2bf(v1.x); r[5] = f2bf(v1.y); r[6] = f2bf(v1.z); r[7] = f2bf(v1.w);
    *reinterpret_cast<u16x8*>(o + i) = r;
}

// ---------------------------------------------------------------------------
// WhT[c][k] = bf16( k<512 ? Wh[k][c] : Wx[k-512][c] ), c<2048, k<576.
// ---------------------------------------------------------------------------
__global__ __launch_bounds__(256)
void conv_WhT(const float* __restrict__ Wh, const float* __restrict__ Wx,
              unsigned short* __restrict__ WhT)
{
    __shared__ float lt[64][65];
    const int tid = threadIdx.x;
    const int c0 = blockIdx.x * 64;
    const int k0 = blockIdx.y * 64;
#pragma unroll
    for (int j = 0; j < 16; ++j) {
        const int lin = tid + 256 * j;
        const int kk = lin >> 6, cc = lin & 63;
        const int k = k0 + kk;
        lt[cc][kk] = (k < 512) ? Wh[(size_t)k * NG + c0 + cc]
                               : Wx[(size_t)(k - 512) * NG + c0 + cc];
    }
    __syncthreads();
    const int c = tid >> 2, kseg = tid & 3;
    unsigned short tmp[16];
#pragma unroll
    for (int m = 0; m < 16; ++m)
        tmp[m] = f2bf(lt[c][kseg * 16 + m]);
    unsigned short* dst = WhT + (size_t)(c0 + c) * KTOT + k0 + kseg * 16;
    *reinterpret_cast<u16x8*>(dst)     = *reinterpret_cast<u16x8*>(tmp);
    *reinterpret_cast<u16x8*>(dst + 8) = *reinterpret_cast<u16x8*>(tmp + 8);
}

// ---------------------------------------------------------------------------
// Attention: one wave per (b,q), registers + butterflies.
// ---------------------------------------------------------------------------
__global__ __launch_bounds__(256)
void attn_kernel(const float* __restrict__ S, const float* __restrict__ Hbuf,
                 const float* __restrict__ s0, float* __restrict__ A)
{
    const int tid  = threadIdx.x;
    const int wv   = tid >> 6;
    const int lane = tid & 63;
    const int b    = blockIdx.x >> 5;
    const int q    = (blockIdx.x & 31) * 4 + wv;

    const float* qrow = (q == 0) ? (s0 + (size_t)b * NU)
                                 : (S + ((size_t)b * NT + (q - 1)) * NU);
    const float4* q4 = reinterpret_cast<const float4*>(qrow);
    const float4 qa = q4[lane], qb = q4[64 + lane];
    const float4* Hb = reinterpret_cast<const float4*>(Hbuf + (size_t)b * NT * NU);

    float sr0 = 0.f, sr1 = 0.f;
    for (int k = 0; k < NT; ++k) {
        const float4* hk = Hb + (size_t)k * 128;
        float4 ha = hk[lane], hc = hk[64 + lane];
        float d = qa.x * ha.x + qa.y * ha.y + qa.z * ha.z + qa.w * ha.w
                + qb.x * hc.x + qb.y * hc.y + qb.z * hc.z + qb.w * hc.w;
#pragma unroll
        for (int o = 32; o; o >>= 1) d += __shfl_xor(d, o);
        if ((k & 63) == lane) { if (k < 64) sr0 = d; else sr1 = d; }
        if ((k & 31) == 31) __syncthreads();
    }

    float m = fmaxf(sr0, sr1);
#pragma unroll
    for (int o = 32; o; o >>= 1) m = fmaxf(m, __shfl_xor(m, o));
    float e0 = expf(sr0 - m), e1 = expf(sr1 - m);
    float s = e0 + e1;
#pragma unroll
    for (int o = 32; o; o >>= 1) s += __shfl_xor(s, o);
    const float inv = 1.f / s;
    e0 *= inv; e1 *= inv;

    float4 acc0 = {0.f, 0.f, 0.f, 0.f}, acc1 = {0.f, 0.f, 0.f, 0.f};
    for (int k = 0; k < 64; ++k) {
        const float wk = __shfl(e0, k);
        const float4* hk = Hb + (size_t)k * 128;
        float4 ha = hk[lane], hc = hk[64 + lane];
        acc0.x += wk * ha.x; acc0.y += wk * ha.y; acc0.z += wk * ha.z; acc0.w += wk * ha.w;
        acc1.x += wk * hc.x; acc1.y += wk * hc.y; acc1.z += wk * hc.z; acc1.w += wk * hc.w;
        if ((k & 31) == 31) __syncthreads();
    }
    for (int k = 0; k < 64; ++k) {
        const float wk = __shfl(e1, k);
        const float4* hk = Hb + (size_t)(64 + k) * 128;
        float4 ha = hk[lane], hc = hk[64 + lane];
        acc0.x += wk * ha.x; acc0.y += wk * ha.y; acc0.z += wk * ha.z; acc0.w += wk * ha.w;
        acc1.x += wk * hc.x; acc1.y += wk * hc.y; acc1.z += wk * hc.z; acc1.w += wk * hc.w;
        if ((k & 31) == 31) __syncthreads();
    }
    float4* Aq = reinterpret_cast<float4*>(A + ((size_t)b * NT + q) * NU);
    Aq[lane] = acc0;
    Aq[64 + lane] = acc1;
}

// ---------------------------------------------------------------------------
// Convert yo=[S|A] (fp32) -> bf16 [8192][1024] (aliases Hbuf; runs after attn)
// ---------------------------------------------------------------------------
__global__ __launch_bounds__(256)
void conv_yo(const float* __restrict__ S, const float* __restrict__ A,
             unsigned short* __restrict__ yo)
{
    const int base = (blockIdx.x * 256 + threadIdx.x) * 8;
    const int row = base >> 10;
    const int col = base & 1023;
    const float* src = (col < 512) ? (S + (size_t)row * NU + col)
                                   : (A + (size_t)row * NU + (col - 512));
    const float4 v0 = reinterpret_cast<const float4*>(src)[0];
    const float4 v1 = reinterpret_cast<const float4*>(src)[1];
    u16x8 o;
    o[0] = f2bf(v0.x); o[1] = f2bf(v0.y); o[2] = f2bf(v0.z); o[3] = f2bf(v0.w);
    o[4] = f2bf(v1.x); o[5] = f2bf(v1.y); o[6] = f2bf(v1.z); o[7] = f2bf(v1.w);
    *reinterpret_cast<u16x8*>(yo + base) = o;
}

// ---------------------------------------------------------------------------
// Transpose dense_W [1024][2000] fp32 -> Wt [2048][1024] bf16 (pad rows zero)
// ---------------------------------------------------------------------------
__global__ __launch_bounds__(256)
void conv_Wt(const float* __restrict__ W, unsigned short* __restrict__ Wt)
{
    __shared__ float lt[64][65];
    const int tid = threadIdx.x;
    const int c0 = blockIdx.x * 64;
    const int k0 = blockIdx.y * 64;
#pragma unroll
    for (int j = 0; j < 16; ++j) {
        const int lin = tid + 256 * j;
        const int kk = lin >> 6, cc = lin & 63;
        const int c = c0 + cc;
        lt[cc][kk] = (c < NV) ? W[(size_t)(k0 + kk) * NV + c] : 0.f;
    }
    __syncthreads();
    const int c = tid >> 2, kseg = tid & 3;
    unsigned short tmp[16];
#pragma unroll
    for (int m = 0; m < 16; ++m)
        tmp[m] = f2bf(lt[c][kseg * 16 + m]);
    unsigned short* dst = Wt + (size_t)(c0 + c) * 1024 + k0 + kseg * 16;
    *reinterpret_cast<u16x8*>(dst)     = *reinterpret_cast<u16x8*>(tmp);
    *reinterpret_cast<u16x8*>(dst + 8) = *reinterpret_cast<u16x8*>(tmp + 8);
}

// ---------------------------------------------------------------------------
// Dense via bf16 MFMA: out[8192][2000] = yo[8192][1024] x W[1024][2000] + b.
// ---------------------------------------------------------------------------
__global__ __launch_bounds__(256)
void dense_mfma(const unsigned short* __restrict__ yo,
                const unsigned short* __restrict__ Wt,
                const float* __restrict__ bias, float* __restrict__ out)
{
    __shared__ unsigned short Asm[128][40];
    __shared__ unsigned short Bsm[128][40];
    const int tid  = threadIdx.x;
    const int wave = tid >> 6, lane = tid & 63;
    const int wm = wave >> 1, wn = wave & 1;
    const int r0 = blockIdx.y * 128, c0 = blockIdx.x * 128;
    const int rr = lane & 15, kh = lane >> 4;

    f32x4 acc[4][4];
#pragma unroll
    for (int m = 0; m < 4; ++m)
#pragma unroll
        for (int n = 0; n < 4; ++n) acc[m][n] = (f32x4){0.f, 0.f, 0.f, 0.f};

    for (int k0 = 0; k0 < 1024; k0 += 32) {
        __syncthreads();
#pragma unroll
        for (int h = 0; h < 2; ++h) {
            const int row = (tid >> 2) + h * 64, seg = tid & 3;
            *reinterpret_cast<uint4*>(&Asm[row][seg * 8]) =
                *reinterpret_cast<const uint4*>(yo + (size_t)(r0 + row) * 1024 + k0 + seg * 8);
            *reinterpret_cast<uint4*>(&Bsm[row][seg * 8]) =
                *reinterpret_cast<const uint4*>(Wt + (size_t)(c0 + row) * 1024 + k0 + seg * 8);
        }
        __syncthreads();
        bf16x8 af[4], bfr[4];
#pragma unroll
        for (int m = 0; m < 4; ++m)
            af[m] = *reinterpret_cast<const bf16x8*>(&Asm[wm * 64 + m * 16 + rr][kh * 8]);
#pragma unroll
        for (int n = 0; n < 4; ++n)
            bfr[n] = *reinterpret_cast<const bf16x8*>(&Bsm[wn * 64 + n * 16 + rr][kh * 8]);
#pragma unroll
        for (int m = 0; m < 4; ++m)
#pragma unroll
            for (int n = 0; n < 4; ++n)
                acc[m][n] = __builtin_amdgcn_mfma_f32_16x16x32_bf16(af[m], bfr[n], acc[m][n], 0, 0, 0);
    }

#pragma unroll
    for (int m = 0; m < 4; ++m) {
#pragma unroll
        for (int n = 0; n < 4; ++n) {
            const int c = c0 + wn * 64 + n * 16 + rr;
            if (c < NV) {
                const float bc = bias[c];
#pragma unroll
                for (int reg = 0; reg < 4; ++reg) {
                    const int r = r0 + wm * 64 + m * 16 + kh * 4 + reg;
                    out[(size_t)r * NV + c] = acc[m][n][reg] + bc;
                }
            }
        }
    }
}

// ---------------------------------------------------------------------------
// In-place row softmax over V=2000 logits.
// ---------------------------------------------------------------------------
__global__ __launch_bounds__(256)
void softmax_rows(float* __restrict__ out)
{
    __shared__ float red[4];
    const int t = threadIdx.x;
    float* row = out + (size_t)blockIdx.x * NV;

    float v[8];
    float m = -INFINITY;
#pragma unroll
    for (int i = 0; i < 8; ++i) {
        const int j = t + 256 * i;
        v[i] = (j < NV) ? row[j] : -INFINITY;
        m = fmaxf(m, v[i]);
    }
#pragma unroll
    for (int o = 32; o; o >>= 1) m = fmaxf(m, __shfl_xor(m, o));
    if ((t & 63) == 0) red[t >> 6] = m;
    __syncthreads();
    m = fmaxf(fmaxf(red[0], red[1]), fmaxf(red[2], red[3]));
    __syncthreads();

    float s = 0.f;
#pragma unroll
    for (int i = 0; i < 8; ++i) {
        const int j = t + 256 * i;
        if (j < NV) { v[i] = expf(v[i] - m); s += v[i]; }
    }
#pragma unroll
    for (int o = 32; o; o >>= 1) s += __shfl_xor(s, o);
    if ((t & 63) == 0) red[t >> 6] = s;
    __syncthreads();
    const float inv = 1.f / (red[0] + red[1] + red[2] + red[3]);
#pragma unroll
    for (int i = 0; i < 8; ++i) {
        const int j = t + 256 * i;
        if (j < NV) row[j] = v[i] * inv;
    }
}

// ---------------------------------------------------------------------------
extern "C" void kernel_launch(void* const* d_in, const int* in_sizes, int n_in,
                              void* d_out, int out_size, void* d_ws, size_t ws_size,
                              hipStream_t stream)
{
    const int*   x       = (const int*)  d_in[0];
    const int*   y       = (const int*)  d_in[1];
    const float* enc_emb = (const float*)d_in[2];
    const float* enc_Wx  = (const float*)d_in[3];
    const float* enc_Wh  = (const float*)d_in[4];
    const float* enc_b   = (const float*)d_in[5];
    const float* dec_emb = (const float*)d_in[6];
    const float* dec_Wx  = (const float*)d_in[7];
    const float* dec_Wh  = (const float*)d_in[8];
    const float* dec_b   = (const float*)d_in[9];
    const float* dns_W   = (const float*)d_in[10];
    const float* dns_b   = (const float*)d_in[11];
    float* out = (float*)d_out;

    float* ws   = (float*)d_ws;
    float* Hbuf = ws;                                  // [B,T,U] fp32 (aliased by yo bf16)
    float* Sbuf = Hbuf + (size_t)NB * NT * NU;
    float* Abuf = Sbuf + (size_t)NB * NT * NU;
    unsigned short* Wt = (unsigned short*)(Abuf + (size_t)NB * NT * NU);  // [2048][1024] bf16
    float* ehp  = (float*)(Wt + (size_t)2048 * 1024);  // enc h ping-pong [2][B,U]
    float* dhp  = ehp + 2 * BU;
    float* cfe  = dhp + 2 * BU;
    float* cfd  = cfe + BU;
    unsigned int* bar0 = (unsigned int*)(cfd + BU);    // 512 flags enc
    unsigned int* bar1 = bar0 + 512;                   // 512 flags dec
    unsigned short* WhT_e = (unsigned short*)(bar1 + 512);          // [2048][576] bf16
    unsigned short* WhT_d = WhT_e + (size_t)2048 * KTOT;            // [2048][576] bf16
    unsigned short* embb_e = WhT_d + (size_t)2048 * KTOT;           // [2000][64] bf16
    unsigned short* embb_d = embb_e + (size_t)NV * NE;              // [2000][64] bf16
    unsigned short* yo = (unsigned short*)Hbuf;        // bf16 [8192][1024], alias

    // flags MUST be zeroed every call (0xAA poison would forge future values)
    hipMemsetAsync(bar0, 0, 2 * 512 * sizeof(unsigned int), stream);

    // allow 96KB dynamic LDS for the LSTM kernel (idempotent host call)
    (void)hipFuncSetAttribute(reinterpret_cast<const void*>(lstm_coop),
                              hipFuncAttributeMaxDynamicSharedMemorySize, SMEM_BYTES);

    // weight/table conversions (independent of LSTMs)
    conv_emb<<<dim3((NV * NE / 8 + 255) / 256), dim3(256), 0, stream>>>(enc_emb, embb_e, NV * NE);
    conv_emb<<<dim3((NV * NE / 8 + 255) / 256), dim3(256), 0, stream>>>(dec_emb, embb_d, NV * NE);
    conv_WhT<<<dim3(32, 9), dim3(256), 0, stream>>>(enc_Wh, enc_Wx, WhT_e);
    conv_WhT<<<dim3(32, 9), dim3(256), 0, stream>>>(dec_Wh, dec_Wx, WhT_d);
    conv_Wt<<<dim3(32, 16), dim3(256), 0, stream>>>(dns_W, Wt);

    const float* nul = nullptr;
    {   // encoder LSTM
        void* args[] = { (void*)&x, (void*)&embb_e, (void*)&WhT_e, (void*)&enc_b,
                         (void*)&nul, (void*)&nul,
                         (void*)&Hbuf, (void*)&ehp, (void*)&cfe, (void*)&bar0 };
        (void)hipLaunchCooperativeKernel(reinterpret_cast<void*>(lstm_coop),
                                         dim3(GRID_LSTM), dim3(512), args,
                                         SMEM_BYTES, stream);
    }
    {   // decoder LSTM: h0 = enc final h (ehp slot 0), c0 = enc final c
        const float* h0 = ehp;
        const float* c0 = cfe;
        void* args[] = { (void*)&y, (void*)&embb_d, (void*)&WhT_d, (void*)&dec_b,
                         (void*)&h0, (void*)&c0,
                         (void*)&Sbuf, (void*)&dhp, (void*)&cfd, (void*)&bar1 };
        (void)hipLaunchCooperativeKernel(reinterpret_cast<void*>(lstm_coop),
                                         dim3(GRID_LSTM), dim3(512), args,
                                         SMEM_BYTES, stream);
    }
    attn_kernel<<<dim3(NB * 32), dim3(256), 0, stream>>>(Sbuf, Hbuf, ehp, Abuf);
    conv_yo<<<dim3(4096), dim3(256), 0, stream>>>(Sbuf, Abuf, yo);
    dense_mfma<<<dim3(16, 64), dim3(256), 0, stream>>>(yo, Wt, dns_b, out);
    softmax_rows<<<dim3(NB * NT), dim3(256), 0, stream>>>(out);
}

// Round 11
// 985.031 us; speedup vs baseline: 2.5139x; 1.0136x over previous
//
#include <hip/hip_runtime.h>
#include <math.h>

#define NB 64       // batch
#define NT 128      // time steps
#define NE 64       // embedding
#define NU 512      // units
#define NG 2048     // 4*U
#define NV 2000     // vocab
#define BU (NB*NU)
#define GRID_LSTM 256
#define KTOT 576        // 512 (h) + 64 (emb) = 18 K-tiles of 32
#define HS 584          // hlds row stride (shorts)
#define WSTRIDE 584     // whb row stride (shorts)
#define SMEM_BYTES (64*WSTRIDE*2 + 16*HS*2 + 2*8*64*4)   // 97536

typedef __attribute__((ext_vector_type(8))) short bf16x8;
typedef __attribute__((ext_vector_type(4))) float f32x4;
typedef __attribute__((ext_vector_type(8))) unsigned short u16x8;

__device__ __forceinline__ unsigned short f2bf(float x) {
    unsigned int u = __float_as_uint(x);
    u += 0x7FFFu + ((u >> 16) & 1u);
    return (unsigned short)(u >> 16);
}
__device__ __forceinline__ float fsigmoid(float x) {
    return __builtin_amdgcn_rcpf(1.f + __expf(-x));
}
__device__ __forceinline__ float ftanh(float x) {
    return 1.f - 2.f * __builtin_amdgcn_rcpf(__expf(2.f * x) + 1.f);
}

// ---------------------------------------------------------------------------
// Fused encoder+decoder cooperative LSTM. R5/R9/R10's PROVEN sync protocol,
// run for 256 monotone steps T (flags never reset; h ping-pong parity
// continues across the boundary). Group rg owns batch rows 8rg..+8 in BOTH
// phases, so the enc->dec handoff (h0=enc final h, c0=enc final c of the
// SAME rows) is group-local: h arrives via the normal T=127 sync step,
// c stays in registers. At the boundary: restage whb from dec weights,
// switch bias/ids/emb pointers, dump enc final h to hfin (for attention).
// ---------------------------------------------------------------------------
__global__ __launch_bounds__(512, 1)
void lstm2_coop(const int* __restrict__ xids, const int* __restrict__ yids,
                const unsigned short* __restrict__ embb_e,
                const unsigned short* __restrict__ embb_d,
                const unsigned short* __restrict__ WhT_e,
                const unsigned short* __restrict__ WhT_d,
                const float* __restrict__ enc_b, const float* __restrict__ dec_b,
                float* __restrict__ Hbuf, float* __restrict__ Sbuf,
                float* __restrict__ hping, float* __restrict__ hfin,
                unsigned int* __restrict__ flags)
{
    extern __shared__ char smem[];
    unsigned short* whb  = (unsigned short*)smem;                      // [64][WSTRIDE]
    unsigned short* hlds = (unsigned short*)(smem + 64 * WSTRIDE * 2); // [16][HS] bf16
    float* zbuf = (float*)(smem + 64 * WSTRIDE * 2 + 16 * HS * 2);     // [2][8][64]

    const int tid  = threadIdx.x;
    const int wv   = tid >> 6;
    const int cl   = tid & 63;
    const int bk   = blockIdx.x;
    const int rg   = bk & 7;                   // group (8 groups x 32 blocks)
    const int cgi  = bk >> 3;                  // 0..31 unit slice
    const int brow0 = rg * 8;
    const int u0    = cgi * 16;

    const int bl  = tid >> 4;                  // tid<128: row
    const int uug = tid & 15;
    float creg = 0.f;
    float b4[4] = {0.f, 0.f, 0.f, 0.f};
    if (tid < 128) {
#pragma unroll
        for (int g = 0; g < 4; ++g) b4[g] = enc_b[g * 512 + u0 + uug];
    }

    // ---- stage B (enc WhT slice -> LDS): col cp, k-chunk ch (72 shorts)
    {
        const int cp = tid >> 3, ch = tid & 7;
        const int cg = (cp >> 4) * 512 + u0 + (cp & 15);
        const uint4* src = reinterpret_cast<const uint4*>(WhT_e + (size_t)cg * KTOT + ch * 72);
        uint4* dst = reinterpret_cast<uint4*>(whb + cp * WSTRIDE + ch * 72);
#pragma unroll
        for (int i = 0; i < 9; ++i) dst[i] = src[i];
    }

    // ---- h(0)=0 bf16, zero pad rows 8-15, stage emb(0) from x
    const int col = wv * 64 + cl;
#pragma unroll
    for (int b = 0; b < 8; ++b) hlds[b * HS + col] = 0;
    for (int i = tid; i < 8 * HS; i += 512) hlds[8 * HS + i] = 0;
    {
        const int idb = xids[(brow0 + wv) * NT + 0];
        hlds[wv * HS + 512 + cl] = embb_e[(size_t)idb * NE + cl];
    }
    unsigned int* fl = flags + rg * 64;

    for (int T = 0; T < 2 * NT; ++T) {
        const int t = T & (NT - 1);
        float* Ho = (T < NT) ? Hbuf : Sbuf;
        __syncthreads();                       // B#0: hlds + whb visible

        // ---- z = [h|emb] @ W via MFMA: wave = (gate wv&3, K-half wv>>2)
        {
            const int g = wv & 3, half = wv >> 2;
            const int rr = cl & 15, kh = cl >> 4;
            f32x4 acc = {0.f, 0.f, 0.f, 0.f};
            const unsigned short* arow = hlds + rr * HS;
            const unsigned short* brow = whb + (g * 16 + rr) * WSTRIDE;
#pragma unroll
            for (int kt = 0; kt < 9; ++kt) {
                const int kb = (half * 9 + kt) * 32 + kh * 8;
                bf16x8 af = *reinterpret_cast<const bf16x8*>(arow + kb);
                bf16x8 bf = *reinterpret_cast<const bf16x8*>(brow + kb);
                acc = __builtin_amdgcn_mfma_f32_16x16x32_bf16(af, bf, acc, 0, 0, 0);
            }
            if (cl < 32) {
#pragma unroll
                for (int reg = 0; reg < 4; ++reg)
                    zbuf[half * 512 + (kh * 4 + reg) * 64 + g * 16 + rr] = acc[reg];
            }
        }
        __syncthreads();                       // B#1: zbuf complete

        // ---- gates + state update + h publish (EXACT proven protocol)
        float h_ = 0.f;
        if (tid < 128) {
            float z[4];
#pragma unroll
            for (int g = 0; g < 4; ++g)
                z[g] = b4[g] + zbuf[bl * 64 + g * 16 + uug]
                             + zbuf[512 + bl * 64 + g * 16 + uug];
            const float i_ = fsigmoid(z[0]);
            const float f_ = fsigmoid(z[1]);
            const float g_ = ftanh(z[2]);
            const float o_ = fsigmoid(z[3]);
            creg = f_ * creg + i_ * g_;
            h_ = o_ * ftanh(creg);
            float* hw = hping + ((T + 1) & 1) * BU;
            __hip_atomic_store(&hw[(brow0 + bl) * NU + u0 + uug], h_,
                               __ATOMIC_RELAXED, __HIP_MEMORY_SCOPE_AGENT);
        }
        if (T == 2 * NT - 1) {
            if (tid < 128)
                Ho[((size_t)(brow0 + bl) * NT + t) * NU + u0 + uug] = h_;
            break;                             // flushed at kernel end
        }

        if (tid < 128)
            asm volatile("s_waitcnt vmcnt(0)" ::: "memory");  // h at coherence pt
        __syncthreads();                       // B#2: all h stores complete

        if (tid < 128 && (tid & 63) == 0)
            __hip_atomic_store(&fl[(tid >> 6) * 32 + cgi], (unsigned)(T + 1),
                               __ATOMIC_RELAXED, __HIP_MEMORY_SCOPE_AGENT);
        if (tid < 128) {                       // off critical path: drain in bg
            Ho[((size_t)(brow0 + bl) * NT + t) * NU + u0 + uug] = h_;
            if (T == NT - 1)                   // enc final h for attention s0
                hfin[(brow0 + bl) * NU + u0 + uug] = h_;
        }

        // ---- stage emb(T+1) (independent of h(T+1): hides in poll window)
        {
            const int Tn = T + 1;
            const int* nids = (Tn < NT) ? xids : yids;
            const unsigned short* nemb = (Tn < NT) ? embb_e : embb_d;
            const int idb = nids[(brow0 + wv) * NT + (Tn & (NT - 1))];
            hlds[wv * HS + 512 + cl] = nemb[(size_t)idb * NE + cl];
        }

        if (wv == 0) {                         // single polling wave per block
            const unsigned target = (unsigned)(T + 1);
            while (true) {
                unsigned v = __hip_atomic_load(&fl[cl], __ATOMIC_RELAXED,
                                               __HIP_MEMORY_SCOPE_AGENT);
#pragma unroll
                for (int o = 16; o; o >>= 1) {
                    unsigned v2 = (unsigned)__shfl_xor((int)v, o);
                    v = v2 < v ? v2 : v;
                }
                if (v >= target) break;
                __builtin_amdgcn_s_sleep(1);
            }
        }
        __syncthreads();                       // B#3: release all waves

        // ---- reload own h slice fp32 -> bf16 into LDS
        {
            const float* hr = hping + ((T + 1) & 1) * BU + (size_t)brow0 * NU;
            float tmp[8];
#pragma unroll
            for (int b = 0; b < 8; ++b)
                tmp[b] = __hip_atomic_load(const_cast<float*>(&hr[b * NU + col]),
                                           __ATOMIC_RELAXED, __HIP_MEMORY_SCOPE_AGENT);
#pragma unroll
            for (int b = 0; b < 8; ++b) hlds[b * HS + col] = f2bf(tmp[b]);
        }

        // ---- enc->dec boundary: restage whb from dec weights, switch bias
        if (T == NT - 1) {
            const int cp = tid >> 3, ch = tid & 7;
            const int cg = (cp >> 4) * 512 + u0 + (cp & 15);
            const uint4* src = reinterpret_cast<const uint4*>(WhT_d + (size_t)cg * KTOT + ch * 72);
            uint4* dst = reinterpret_cast<uint4*>(whb + cp * WSTRIDE + ch * 72);
#pragma unroll
            for (int i = 0; i < 9; ++i) dst[i] = src[i];
            if (tid < 128) {
#pragma unroll
                for (int g = 0; g < 4; ++g) b4[g] = dec_b[g * 512 + u0 + uug];
            }
        }
    }
}

// ---------------------------------------------------------------------------
// Both emb tables fp32 -> bf16, one launch. nbh blocks per table.
// ---------------------------------------------------------------------------
__global__ __launch_bounds__(256)
void conv_emb2(const float* __restrict__ e0, const float* __restrict__ e1,
               unsigned short* __restrict__ o0, unsigned short* __restrict__ o1,
               int n, int nbh)
{
    int b = blockIdx.x;
    const float* e = e0; unsigned short* o = o0;
    if (b >= nbh) { b -= nbh; e = e1; o = o1; }
    const int i = (b * 256 + threadIdx.x) * 8;
    if (i >= n) return;
    const float4 v0 = reinterpret_cast<const float4*>(e + i)[0];
    const float4 v1 = reinterpret_cast<const float4*>(e + i)[1];
    u16x8 r;
    r[0] = f2bf(v0.x); r[1] = f2bf(v0.y); r[2] = f2bf(v0.z); r[3] = f2bf(v0.w);
    r[4] = f2bf(v1.x); r[5] = f2bf(v1.y); r[6] = f2bf(v1.z); r[7] = f2bf(v1.w);
    *reinterpret_cast<u16x8*>(o + i) = r;
}

// ---------------------------------------------------------------------------
// WhT[c][k] = bf16( k<512 ? Wh[k][c] : Wx[k-512][c] ); z selects enc/dec.
// ---------------------------------------------------------------------------
__global__ __launch_bounds__(256)
void conv_WhT2(const float* __restrict__ Wh_e, const float* __restrict__ Wx_e,
               const float* __restrict__ Wh_d, const float* __restrict__ Wx_d,
               unsigned short* __restrict__ WhT_e, unsigned short* __restrict__ WhT_d)
{
    __shared__ float lt[64][65];
    const float* Wh = (blockIdx.z == 0) ? Wh_e : Wh_d;
    const float* Wx = (blockIdx.z == 0) ? Wx_e : Wx_d;
    unsigned short* WhT = (blockIdx.z == 0) ? WhT_e : WhT_d;
    const int tid = threadIdx.x;
    const int c0 = blockIdx.x * 64;
    const int k0 = blockIdx.y * 64;
#pragma unroll
    for (int j = 0; j < 16; ++j) {
        const int lin = tid + 256 * j;
        const int kk = lin >> 6, cc = lin & 63;
        const int k = k0 + kk;
        lt[cc][kk] = (k < 512) ? Wh[(size_t)k * NG + c0 + cc]
                               : Wx[(size_t)(k - 512) * NG + c0 + cc];
    }
    __syncthreads();
    const int c = tid >> 2, kseg = tid & 3;
    unsigned short tmp[16];
#pragma unroll
    for (int m = 0; m < 16; ++m)
        tmp[m] = f2bf(lt[c][kseg * 16 + m]);
    unsigned short* dst = WhT + (size_t)(c0 + c) * KTOT + k0 + kseg * 16;
    *reinterpret_cast<u16x8*>(dst)     = *reinterpret_cast<u16x8*>(tmp);
    *reinterpret_cast<u16x8*>(dst + 8) = *reinterpret_cast<u16x8*>(tmp + 8);
}

// ---------------------------------------------------------------------------
// Attention: one wave per (b,q), registers + butterflies.
// ---------------------------------------------------------------------------
__global__ __launch_bounds__(256)
void attn_kernel(const float* __restrict__ S, const float* __restrict__ Hbuf,
                 const float* __restrict__ s0, float* __restrict__ A)
{
    const int tid  = threadIdx.x;
    const int wv   = tid >> 6;
    const int lane = tid & 63;
    const int b    = blockIdx.x >> 5;
    const int q    = (blockIdx.x & 31) * 4 + wv;

    const float* qrow = (q == 0) ? (s0 + (size_t)b * NU)
                                 : (S + ((size_t)b * NT + (q - 1)) * NU);
    const float4* q4 = reinterpret_cast<const float4*>(qrow);
    const float4 qa = q4[lane], qb = q4[64 + lane];
    const float4* Hb = reinterpret_cast<const float4*>(Hbuf + (size_t)b * NT * NU);

    float sr0 = 0.f, sr1 = 0.f;
    for (int k = 0; k < NT; ++k) {
        const float4* hk = Hb + (size_t)k * 128;
        float4 ha = hk[lane], hc = hk[64 + lane];
        float d = qa.x * ha.x + qa.y * ha.y + qa.z * ha.z + qa.w * ha.w
                + qb.x * hc.x + qb.y * hc.y + qb.z * hc.z + qb.w * hc.w;
#pragma unroll
        for (int o = 32; o; o >>= 1) d += __shfl_xor(d, o);
        if ((k & 63) == lane) { if (k < 64) sr0 = d; else sr1 = d; }
        if ((k & 31) == 31) __syncthreads();
    }

    float m = fmaxf(sr0, sr1);
#pragma unroll
    for (int o = 32; o; o >>= 1) m = fmaxf(m, __shfl_xor(m, o));
    float e0 = expf(sr0 - m), e1 = expf(sr1 - m);
    float s = e0 + e1;
#pragma unroll
    for (int o = 32; o; o >>= 1) s += __shfl_xor(s, o);
    const float inv = 1.f / s;
    e0 *= inv; e1 *= inv;

    float4 acc0 = {0.f, 0.f, 0.f, 0.f}, acc1 = {0.f, 0.f, 0.f, 0.f};
    for (int k = 0; k < 64; ++k) {
        const float wk = __shfl(e0, k);
        const float4* hk = Hb + (size_t)k * 128;
        float4 ha = hk[lane], hc = hk[64 + lane];
        acc0.x += wk * ha.x; acc0.y += wk * ha.y; acc0.z += wk * ha.z; acc0.w += wk * ha.w;
        acc1.x += wk * hc.x; acc1.y += wk * hc.y; acc1.z += wk * hc.z; acc1.w += wk * hc.w;
        if ((k & 31) == 31) __syncthreads();
    }
    for (int k = 0; k < 64; ++k) {
        const float wk = __shfl(e1, k);
        const float4* hk = Hb + (size_t)(64 + k) * 128;
        float4 ha = hk[lane], hc = hk[64 + lane];
        acc0.x += wk * ha.x; acc0.y += wk * ha.y; acc0.z += wk * ha.z; acc0.w += wk * ha.w;
        acc1.x += wk * hc.x; acc1.y += wk * hc.y; acc1.z += wk * hc.z; acc1.w += wk * hc.w;
        if ((k & 31) == 31) __syncthreads();
    }
    float4* Aq = reinterpret_cast<float4*>(A + ((size_t)b * NT + q) * NU);
    Aq[lane] = acc0;
    Aq[64 + lane] = acc1;
}

// ---------------------------------------------------------------------------
// Transpose dense_W [1024][2000] fp32 -> Wt [2048][1024] bf16 (pad rows zero)
// ---------------------------------------------------------------------------
__global__ __launch_bounds__(256)
void conv_Wt(const float* __restrict__ W, unsigned short* __restrict__ Wt)
{
    __shared__ float lt[64][65];
    const int tid = threadIdx.x;
    const int c0 = blockIdx.x * 64;
    const int k0 = blockIdx.y * 64;
#pragma unroll
    for (int j = 0; j < 16; ++j) {
        const int lin = tid + 256 * j;
        const int kk = lin >> 6, cc = lin & 63;
        const int c = c0 + cc;
        lt[cc][kk] = (c < NV) ? W[(size_t)(k0 + kk) * NV + c] : 0.f;
    }
    __syncthreads();
    const int c = tid >> 2, kseg = tid & 3;
    unsigned short tmp[16];
#pragma unroll
    for (int m = 0; m < 16; ++m)
        tmp[m] = f2bf(lt[c][kseg * 16 + m]);
    unsigned short* dst = Wt + (size_t)(c0 + c) * 1024 + k0 + kseg * 16;
    *reinterpret_cast<u16x8*>(dst)     = *reinterpret_cast<u16x8*>(tmp);
    *reinterpret_cast<u16x8*>(dst + 8) = *reinterpret_cast<u16x8*>(tmp + 8);
}

// ---------------------------------------------------------------------------
// Dense via bf16 MFMA, A staged directly from fp32 S|A with in-register
// convert (replaces the conv_yo pass; identical rounding).
// ---------------------------------------------------------------------------
__global__ __launch_bounds__(256)
void dense_mfma(const float* __restrict__ S, const float* __restrict__ A,
                const unsigned short* __restrict__ Wt,
                const float* __restrict__ bias, float* __restrict__ out)
{
    __shared__ unsigned short Asm[128][40];
    __shared__ unsigned short Bsm[128][40];
    const int tid  = threadIdx.x;
    const int wave = tid >> 6, lane = tid & 63;
    const int wm = wave >> 1, wn = wave & 1;
    const int r0 = blockIdx.y * 128, c0 = blockIdx.x * 128;
    const int rr = lane & 15, kh = lane >> 4;

    f32x4 acc[4][4];
#pragma unroll
    for (int m = 0; m < 4; ++m)
#pragma unroll
        for (int n = 0; n < 4; ++n) acc[m][n] = (f32x4){0.f, 0.f, 0.f, 0.f};

    for (int k0 = 0; k0 < 1024; k0 += 32) {
        __syncthreads();
#pragma unroll
        for (int h = 0; h < 2; ++h) {
            const int row = (tid >> 2) + h * 64, seg = tid & 3;
            const int kc = k0 + seg * 8;
            const float* asrc = (kc < 512) ? (S + (size_t)(r0 + row) * NU + kc)
                                           : (A + (size_t)(r0 + row) * NU + (kc - 512));
            const float4 a0 = reinterpret_cast<const float4*>(asrc)[0];
            const float4 a1 = reinterpret_cast<const float4*>(asrc)[1];
            u16x8 av;
            av[0] = f2bf(a0.x); av[1] = f2bf(a0.y); av[2] = f2bf(a0.z); av[3] = f2bf(a0.w);
            av[4] = f2bf(a1.x); av[5] = f2bf(a1.y); av[6] = f2bf(a1.z); av[7] = f2bf(a1.w);
            *reinterpret_cast<u16x8*>(&Asm[row][seg * 8]) = av;
            *reinterpret_cast<uint4*>(&Bsm[row][seg * 8]) =
                *reinterpret_cast<const uint4*>(Wt + (size_t)(c0 + row) * 1024 + k0 + seg * 8);
        }
        __syncthreads();
        bf16x8 af[4], bfr[4];
#pragma unroll
        for (int m = 0; m < 4; ++m)
            af[m] = *reinterpret_cast<const bf16x8*>(&Asm[wm * 64 + m * 16 + rr][kh * 8]);
#pragma unroll
        for (int n = 0; n < 4; ++n)
            bfr[n] = *reinterpret_cast<const bf16x8*>(&Bsm[wn * 64 + n * 16 + rr][kh * 8]);
#pragma unroll
        for (int m = 0; m < 4; ++m)
#pragma unroll
            for (int n = 0; n < 4; ++n)
                acc[m][n] = __builtin_amdgcn_mfma_f32_16x16x32_bf16(af[m], bfr[n], acc[m][n], 0, 0, 0);
    }

#pragma unroll
    for (int m = 0; m < 4; ++m) {
#pragma unroll
        for (int n = 0; n < 4; ++n) {
            const int c = c0 + wn * 64 + n * 16 + rr;
            if (c < NV) {
                const float bc = bias[c];
#pragma unroll
                for (int reg = 0; reg < 4; ++reg) {
                    const int r = r0 + wm * 64 + m * 16 + kh * 4 + reg;
                    out[(size_t)r * NV + c] = acc[m][n][reg] + bc;
                }
            }
        }
    }
}

// ---------------------------------------------------------------------------
// In-place row softmax over V=2000 logits.
// ---------------------------------------------------------------------------
__global__ __launch_bounds__(256)
void softmax_rows(float* __restrict__ out)
{
    __shared__ float red[4];
    const int t = threadIdx.x;
    float* row = out + (size_t)blockIdx.x * NV;

    float v[8];
    float m = -INFINITY;
#pragma unroll
    for (int i = 0; i < 8; ++i) {
        const int j = t + 256 * i;
        v[i] = (j < NV) ? row[j] : -INFINITY;
        m = fmaxf(m, v[i]);
    }
#pragma unroll
    for (int o = 32; o; o >>= 1) m = fmaxf(m, __shfl_xor(m, o));
    if ((t & 63) == 0) red[t >> 6] = m;
    __syncthreads();
    m = fmaxf(fmaxf(red[0], red[1]), fmaxf(red[2], red[3]));
    __syncthreads();

    float s = 0.f;
#pragma unroll
    for (int i = 0; i < 8; ++i) {
        const int j = t + 256 * i;
        if (j < NV) { v[i] = expf(v[i] - m); s += v[i]; }
    }
#pragma unroll
    for (int o = 32; o; o >>= 1) s += __shfl_xor(s, o);
    if ((t & 63) == 0) red[t >> 6] = s;
    __syncthreads();
    const float inv = 1.f / (red[0] + red[1] + red[2] + red[3]);
#pragma unroll
    for (int i = 0; i < 8; ++i) {
        const int j = t + 256 * i;
        if (j < NV) row[j] = v[i] * inv;
    }
}

// ---------------------------------------------------------------------------
extern "C" void kernel_launch(void* const* d_in, const int* in_sizes, int n_in,
                              void* d_out, int out_size, void* d_ws, size_t ws_size,
                              hipStream_t stream)
{
    const int*   x       = (const int*)  d_in[0];
    const int*   y       = (const int*)  d_in[1];
    const float* enc_emb = (const float*)d_in[2];
    const float* enc_Wx  = (const float*)d_in[3];
    const float* enc_Wh  = (const float*)d_in[4];
    const float* enc_b   = (const float*)d_in[5];
    const float* dec_emb = (const float*)d_in[6];
    const float* dec_Wx  = (const float*)d_in[7];
    const float* dec_Wh  = (const float*)d_in[8];
    const float* dec_b   = (const float*)d_in[9];
    const float* dns_W   = (const float*)d_in[10];
    const float* dns_b   = (const float*)d_in[11];
    float* out = (float*)d_out;

    float* ws   = (float*)d_ws;
    float* Hbuf = ws;                                  // [B,T,U] fp32
    float* Sbuf = Hbuf + (size_t)NB * NT * NU;
    float* Abuf = Sbuf + (size_t)NB * NT * NU;
    unsigned short* Wt = (unsigned short*)(Abuf + (size_t)NB * NT * NU);  // [2048][1024]
    float* hping = (float*)(Wt + (size_t)2048 * 1024); // [2][B,U]
    float* hfin  = hping + 2 * BU;                     // enc final h
    unsigned int* bar0 = (unsigned int*)(hfin + BU);   // 512 flags (monotone 1..255)
    unsigned short* WhT_e = (unsigned short*)(bar0 + 512);
    unsigned short* WhT_d = WhT_e + (size_t)2048 * KTOT;
    unsigned short* embb_e = WhT_d + (size_t)2048 * KTOT;
    unsigned short* embb_d = embb_e + (size_t)NV * NE;

    // flags MUST be zeroed every call (0xAA poison would forge future values)
    hipMemsetAsync(bar0, 0, 512 * sizeof(unsigned int), stream);

    (void)hipFuncSetAttribute(reinterpret_cast<const void*>(lstm2_coop),
                              hipFuncAttributeMaxDynamicSharedMemorySize, SMEM_BYTES);

    // one-time conversions
    const int nemb = NV * NE, nbh = (nemb / 8 + 255) / 256;
    conv_emb2<<<dim3(2 * nbh), dim3(256), 0, stream>>>(enc_emb, dec_emb, embb_e, embb_d, nemb, nbh);
    conv_WhT2<<<dim3(32, 9, 2), dim3(256), 0, stream>>>(enc_Wh, enc_Wx, dec_Wh, dec_Wx, WhT_e, WhT_d);
    conv_Wt<<<dim3(32, 16), dim3(256), 0, stream>>>(dns_W, Wt);

    {   // fused encoder+decoder LSTM
        void* args[] = { (void*)&x, (void*)&y, (void*)&embb_e, (void*)&embb_d,
                         (void*)&WhT_e, (void*)&WhT_d, (void*)&enc_b, (void*)&dec_b,
                         (void*)&Hbuf, (void*)&Sbuf, (void*)&hping, (void*)&hfin,
                         (void*)&bar0 };
        (void)hipLaunchCooperativeKernel(reinterpret_cast<void*>(lstm2_coop),
                                         dim3(GRID_LSTM), dim3(512), args,
                                         SMEM_BYTES, stream);
    }
    attn_kernel<<<dim3(NB * 32), dim3(256), 0, stream>>>(Sbuf, Hbuf, hfin, Abuf);
    dense_mfma<<<dim3(16, 64), dim3(256), 0, stream>>>(Sbuf, Abuf, Wt, dns_b, out);
    softmax_rows<<<dim3(NB * NT), dim3(256), 0, stream>>>(out);
}

// Round 12
// 880.741 us; speedup vs baseline: 2.8116x; 1.1184x over previous
//
#include <hip/hip_runtime.h>
#include <math.h>

#define NB 64       // batch
#define NT 128      // time steps
#define NE 64       // embedding
#define NU 512      // units
#define NG 2048     // 4*U
#define NV 2000     // vocab
#define BU (NB*NU)
#define GRID_LSTM 256
#define KTOT 576        // 512 (h) + 64 (emb) = 18 K-tiles of 32
#define HS 584          // hlds row stride (shorts)
#define WSTRIDE 584     // whb row stride (shorts)
#define SMEM_BYTES (64*WSTRIDE*2 + 16*HS*2 + 2*8*64*4)   // 97536

// attn_mfma dynamic LDS layout (bytes)
#define ASSC 129        // scores stride (f32)
#define APB  136        // P / B-chunk stride (bf16)
#define OFF_SSC 0                       // [128][129] f32  (66048 B) / B-chunk [128][136] bf16
#define OFF_PB  66048                   // [128][136] bf16 (34816 B)
#define OFF_ASM 100864                  // [128][40] bf16  (10240 B)
#define OFF_BSM 111104                  // [128][40] bf16  (10240 B)
#define SMEM_ATT 121344

typedef __attribute__((ext_vector_type(8))) short bf16x8;
typedef __attribute__((ext_vector_type(4))) float f32x4;
typedef __attribute__((ext_vector_type(8))) unsigned short u16x8;

__device__ __forceinline__ unsigned short f2bf(float x) {
    unsigned int u = __float_as_uint(x);
    u += 0x7FFFu + ((u >> 16) & 1u);
    return (unsigned short)(u >> 16);
}
__device__ __forceinline__ float fsigmoid(float x) {
    return __builtin_amdgcn_rcpf(1.f + __expf(-x));
}
__device__ __forceinline__ float ftanh(float x) {
    return 1.f - 2.f * __builtin_amdgcn_rcpf(__expf(2.f * x) + 1.f);
}

// ---------------------------------------------------------------------------
// Fused encoder+decoder cooperative LSTM (R11, PROVEN). Only change: decoder
// phase also writes h as bf16 into yo[:,0:512] (off critical path; same
// rounding conv_yo used -> bit-identical dense input).
// ---------------------------------------------------------------------------
__global__ __launch_bounds__(512, 1)
void lstm2_coop(const int* __restrict__ xids, const int* __restrict__ yids,
                const unsigned short* __restrict__ embb_e,
                const unsigned short* __restrict__ embb_d,
                const unsigned short* __restrict__ WhT_e,
                const unsigned short* __restrict__ WhT_d,
                const float* __restrict__ enc_b, const float* __restrict__ dec_b,
                float* __restrict__ Hbuf, float* __restrict__ Sbuf,
                float* __restrict__ hping, float* __restrict__ hfin,
                unsigned short* __restrict__ yo,
                unsigned int* __restrict__ flags)
{
    extern __shared__ char smem[];
    unsigned short* whb  = (unsigned short*)smem;                      // [64][WSTRIDE]
    unsigned short* hlds = (unsigned short*)(smem + 64 * WSTRIDE * 2); // [16][HS] bf16
    float* zbuf = (float*)(smem + 64 * WSTRIDE * 2 + 16 * HS * 2);     // [2][8][64]

    const int tid  = threadIdx.x;
    const int wv   = tid >> 6;
    const int cl   = tid & 63;
    const int bk   = blockIdx.x;
    const int rg   = bk & 7;                   // group (8 groups x 32 blocks)
    const int cgi  = bk >> 3;                  // 0..31 unit slice
    const int brow0 = rg * 8;
    const int u0    = cgi * 16;

    const int bl  = tid >> 4;                  // tid<128: row
    const int uug = tid & 15;
    float creg = 0.f;
    float b4[4] = {0.f, 0.f, 0.f, 0.f};
    if (tid < 128) {
#pragma unroll
        for (int g = 0; g < 4; ++g) b4[g] = enc_b[g * 512 + u0 + uug];
    }

    // ---- stage B (enc WhT slice -> LDS): col cp, k-chunk ch (72 shorts)
    {
        const int cp = tid >> 3, ch = tid & 7;
        const int cg = (cp >> 4) * 512 + u0 + (cp & 15);
        const uint4* src = reinterpret_cast<const uint4*>(WhT_e + (size_t)cg * KTOT + ch * 72);
        uint4* dst = reinterpret_cast<uint4*>(whb + cp * WSTRIDE + ch * 72);
#pragma unroll
        for (int i = 0; i < 9; ++i) dst[i] = src[i];
    }

    // ---- h(0)=0 bf16, zero pad rows 8-15, stage emb(0) from x
    const int col = wv * 64 + cl;
#pragma unroll
    for (int b = 0; b < 8; ++b) hlds[b * HS + col] = 0;
    for (int i = tid; i < 8 * HS; i += 512) hlds[8 * HS + i] = 0;
    {
        const int idb = xids[(brow0 + wv) * NT + 0];
        hlds[wv * HS + 512 + cl] = embb_e[(size_t)idb * NE + cl];
    }
    unsigned int* fl = flags + rg * 64;

    for (int T = 0; T < 2 * NT; ++T) {
        const int t = T & (NT - 1);
        float* Ho = (T < NT) ? Hbuf : Sbuf;
        __syncthreads();                       // B#0: hlds + whb visible

        // ---- z = [h|emb] @ W via MFMA: wave = (gate wv&3, K-half wv>>2)
        {
            const int g = wv & 3, half = wv >> 2;
            const int rr = cl & 15, kh = cl >> 4;
            f32x4 acc = {0.f, 0.f, 0.f, 0.f};
            const unsigned short* arow = hlds + rr * HS;
            const unsigned short* brow = whb + (g * 16 + rr) * WSTRIDE;
#pragma unroll
            for (int kt = 0; kt < 9; ++kt) {
                const int kb = (half * 9 + kt) * 32 + kh * 8;
                bf16x8 af = *reinterpret_cast<const bf16x8*>(arow + kb);
                bf16x8 bf = *reinterpret_cast<const bf16x8*>(brow + kb);
                acc = __builtin_amdgcn_mfma_f32_16x16x32_bf16(af, bf, acc, 0, 0, 0);
            }
            if (cl < 32) {
#pragma unroll
                for (int reg = 0; reg < 4; ++reg)
                    zbuf[half * 512 + (kh * 4 + reg) * 64 + g * 16 + rr] = acc[reg];
            }
        }
        __syncthreads();                       // B#1: zbuf complete

        // ---- gates + state update + h publish (EXACT proven protocol)
        float h_ = 0.f;
        if (tid < 128) {
            float z[4];
#pragma unroll
            for (int g = 0; g < 4; ++g)
                z[g] = b4[g] + zbuf[bl * 64 + g * 16 + uug]
                             + zbuf[512 + bl * 64 + g * 16 + uug];
            const float i_ = fsigmoid(z[0]);
            const float f_ = fsigmoid(z[1]);
            const float g_ = ftanh(z[2]);
            const float o_ = fsigmoid(z[3]);
            creg = f_ * creg + i_ * g_;
            h_ = o_ * ftanh(creg);
            float* hw = hping + ((T + 1) & 1) * BU;
            __hip_atomic_store(&hw[(brow0 + bl) * NU + u0 + uug], h_,
                               __ATOMIC_RELAXED, __HIP_MEMORY_SCOPE_AGENT);
        }
        if (T == 2 * NT - 1) {
            if (tid < 128) {
                const size_t r = (size_t)(brow0 + bl) * NT + t;
                Ho[r * NU + u0 + uug] = h_;
                yo[r * 1024 + u0 + uug] = f2bf(h_);
            }
            break;                             // flushed at kernel end
        }

        if (tid < 128)
            asm volatile("s_waitcnt vmcnt(0)" ::: "memory");  // h at coherence pt
        __syncthreads();                       // B#2: all h stores complete

        if (tid < 128 && (tid & 63) == 0)
            __hip_atomic_store(&fl[(tid >> 6) * 32 + cgi], (unsigned)(T + 1),
                               __ATOMIC_RELAXED, __HIP_MEMORY_SCOPE_AGENT);
        if (tid < 128) {                       // off critical path: drain in bg
            const size_t r = (size_t)(brow0 + bl) * NT + t;
            Ho[r * NU + u0 + uug] = h_;
            if (T >= NT) yo[r * 1024 + u0 + uug] = f2bf(h_);
            if (T == NT - 1)                   // enc final h for attention s0
                hfin[(brow0 + bl) * NU + u0 + uug] = h_;
        }

        // ---- stage emb(T+1) (independent of h(T+1): hides in poll window)
        {
            const int Tn = T + 1;
            const int* nids = (Tn < NT) ? xids : yids;
            const unsigned short* nemb = (Tn < NT) ? embb_e : embb_d;
            const int idb = nids[(brow0 + wv) * NT + (Tn & (NT - 1))];
            hlds[wv * HS + 512 + cl] = nemb[(size_t)idb * NE + cl];
        }

        if (wv == 0) {                         // single polling wave per block
            const unsigned target = (unsigned)(T + 1);
            while (true) {
                unsigned v = __hip_atomic_load(&fl[cl], __ATOMIC_RELAXED,
                                               __HIP_MEMORY_SCOPE_AGENT);
#pragma unroll
                for (int o = 16; o; o >>= 1) {
                    unsigned v2 = (unsigned)__shfl_xor((int)v, o);
                    v = v2 < v ? v2 : v;
                }
                if (v >= target) break;
                __builtin_amdgcn_s_sleep(1);
            }
        }
        __syncthreads();                       // B#3: release all waves

        // ---- reload own h slice fp32 -> bf16 into LDS
        {
            const float* hr = hping + ((T + 1) & 1) * BU + (size_t)brow0 * NU;
            float tmp[8];
#pragma unroll
            for (int b = 0; b < 8; ++b)
                tmp[b] = __hip_atomic_load(const_cast<float*>(&hr[b * NU + col]),
                                           __ATOMIC_RELAXED, __HIP_MEMORY_SCOPE_AGENT);
#pragma unroll
            for (int b = 0; b < 8; ++b) hlds[b * HS + col] = f2bf(tmp[b]);
        }

        // ---- enc->dec boundary: restage whb from dec weights, switch bias
        if (T == NT - 1) {
            const int cp = tid >> 3, ch = tid & 7;
            const int cg = (cp >> 4) * 512 + u0 + (cp & 15);
            const uint4* src = reinterpret_cast<const uint4*>(WhT_d + (size_t)cg * KTOT + ch * 72);
            uint4* dst = reinterpret_cast<uint4*>(whb + cp * WSTRIDE + ch * 72);
#pragma unroll
            for (int i = 0; i < 9; ++i) dst[i] = src[i];
            if (tid < 128) {
#pragma unroll
                for (int g = 0; g < 4; ++g) b4[g] = dec_b[g * 512 + u0 + uug];
            }
        }
    }
}

// ---------------------------------------------------------------------------
// MFMA attention: one block per batch b, 4 waves (2x2). Phase 1: scores
// (128q x 128k, K=512) — H[b] row-major [k][u] IS the proven B layout.
// Phase 2: row softmax in LDS, P -> bf16. Phase 3: A = P @ H (128q x 512u,
// K=128k), H-chunk transposed into LDS ([u][k]). Output -> yo[:,512:] bf16.
// Frag mappings identical to proven dense_mfma.
// ---------------------------------------------------------------------------
__global__ __launch_bounds__(256)
void attn_mfma(const float* __restrict__ S, const float* __restrict__ Hbuf,
               const float* __restrict__ s0, unsigned short* __restrict__ yo)
{
    extern __shared__ char smem[];
    float* Ssc = (float*)(smem + OFF_SSC);               // [128][129] f32
    unsigned short* Bc  = (unsigned short*)(smem + OFF_SSC);  // later: [128][136] bf16
    unsigned short* Pb  = (unsigned short*)(smem + OFF_PB);   // [128][136] bf16
    unsigned short* Asm_ = (unsigned short*)(smem + OFF_ASM); // [128][40]
    unsigned short* Bsm_ = (unsigned short*)(smem + OFF_BSM); // [128][40]

    const int tid  = threadIdx.x;
    const int wave = tid >> 6, lane = tid & 63;
    const int wm = wave >> 1, wn = wave & 1;
    const int rr = lane & 15, kh = lane >> 4;
    const int b = blockIdx.x;
    const float* Hb = Hbuf + (size_t)b * NT * NU;

    // ================= Phase 1: scores = S_ @ H^T =================
    f32x4 acc[4][4];
#pragma unroll
    for (int m = 0; m < 4; ++m)
#pragma unroll
        for (int n = 0; n < 4; ++n) acc[m][n] = (f32x4){0.f, 0.f, 0.f, 0.f};

    for (int k0 = 0; k0 < 512; k0 += 32) {
        __syncthreads();
#pragma unroll
        for (int h = 0; h < 2; ++h) {
            const int row = (tid >> 2) + h * 64, seg = tid & 3;
            const float* qsrc = (row == 0) ? (s0 + (size_t)b * NU)
                                           : (S + ((size_t)b * NT + row - 1) * NU);
            const float4 a0 = reinterpret_cast<const float4*>(qsrc + k0 + seg * 8)[0];
            const float4 a1 = reinterpret_cast<const float4*>(qsrc + k0 + seg * 8)[1];
            u16x8 av;
            av[0] = f2bf(a0.x); av[1] = f2bf(a0.y); av[2] = f2bf(a0.z); av[3] = f2bf(a0.w);
            av[4] = f2bf(a1.x); av[5] = f2bf(a1.y); av[6] = f2bf(a1.z); av[7] = f2bf(a1.w);
            *reinterpret_cast<u16x8*>(Asm_ + row * 40 + seg * 8) = av;
            const float4 b0 = reinterpret_cast<const float4*>(Hb + (size_t)row * NU + k0 + seg * 8)[0];
            const float4 b1 = reinterpret_cast<const float4*>(Hb + (size_t)row * NU + k0 + seg * 8)[1];
            u16x8 bv;
            bv[0] = f2bf(b0.x); bv[1] = f2bf(b0.y); bv[2] = f2bf(b0.z); bv[3] = f2bf(b0.w);
            bv[4] = f2bf(b1.x); bv[5] = f2bf(b1.y); bv[6] = f2bf(b1.z); bv[7] = f2bf(b1.w);
            *reinterpret_cast<u16x8*>(Bsm_ + row * 40 + seg * 8) = bv;
        }
        __syncthreads();
        bf16x8 af[4], bfr[4];
#pragma unroll
        for (int m = 0; m < 4; ++m)
            af[m] = *reinterpret_cast<const bf16x8*>(Asm_ + (wm * 64 + m * 16 + rr) * 40 + kh * 8);
#pragma unroll
        for (int n = 0; n < 4; ++n)
            bfr[n] = *reinterpret_cast<const bf16x8*>(Bsm_ + (wn * 64 + n * 16 + rr) * 40 + kh * 8);
#pragma unroll
        for (int m = 0; m < 4; ++m)
#pragma unroll
            for (int n = 0; n < 4; ++n)
                acc[m][n] = __builtin_amdgcn_mfma_f32_16x16x32_bf16(af[m], bfr[n], acc[m][n], 0, 0, 0);
    }
    __syncthreads();
#pragma unroll
    for (int m = 0; m < 4; ++m)
#pragma unroll
        for (int n = 0; n < 4; ++n)
#pragma unroll
            for (int reg = 0; reg < 4; ++reg)
                Ssc[(wm * 64 + m * 16 + kh * 4 + reg) * ASSC + wn * 64 + n * 16 + rr] = acc[m][n][reg];
    __syncthreads();

    // ================= Phase 2: row softmax -> Pb (bf16) =================
    {
        const int row = tid >> 1, half = tid & 1;
        float* srow = Ssc + row * ASSC + half * 64;
        float mx = -INFINITY;
#pragma unroll 8
        for (int j = 0; j < 64; ++j) mx = fmaxf(mx, srow[j]);
        mx = fmaxf(mx, __shfl_xor(mx, 1));
        float sum = 0.f;
#pragma unroll 8
        for (int j = 0; j < 64; ++j) { float e = __expf(srow[j] - mx); srow[j] = e; sum += e; }
        sum += __shfl_xor(sum, 1);
        const float inv = 1.f / sum;
#pragma unroll 8
        for (int j = 0; j < 64; ++j)
            Pb[row * APB + half * 64 + j] = f2bf(srow[j] * inv);
    }

    // ================= Phase 3: A = P @ H, output bf16 =================
    for (int nc = 0; nc < 4; ++nc) {
        const int uc0 = nc * 128;
        __syncthreads();                   // Bc region free (prev reads done)
        // stage H-chunk transposed: Bc[u][k], u 0..127, k 0..127
#pragma unroll
        for (int c4 = 0; c4 < 4; ++c4) {
            const int kk = (tid >> 3) + 32 * c4;
            const int u0t = (tid & 7) * 16;
            const float* hsrc = Hb + (size_t)kk * NU + uc0 + u0t;
#pragma unroll
            for (int q4 = 0; q4 < 4; ++q4) {
                const float4 v = reinterpret_cast<const float4*>(hsrc)[q4];
                Bc[(u0t + q4 * 4 + 0) * APB + kk] = f2bf(v.x);
                Bc[(u0t + q4 * 4 + 1) * APB + kk] = f2bf(v.y);
                Bc[(u0t + q4 * 4 + 2) * APB + kk] = f2bf(v.z);
                Bc[(u0t + q4 * 4 + 3) * APB + kk] = f2bf(v.w);
            }
        }
        __syncthreads();

        f32x4 oacc[4][4];
#pragma unroll
        for (int m = 0; m < 4; ++m)
#pragma unroll
            for (int n = 0; n < 4; ++n) oacc[m][n] = (f32x4){0.f, 0.f, 0.f, 0.f};
#pragma unroll
        for (int ks = 0; ks < 4; ++ks) {
            bf16x8 af[4], bfr[4];
#pragma unroll
            for (int m = 0; m < 4; ++m)
                af[m] = *reinterpret_cast<const bf16x8*>(Pb + (wm * 64 + m * 16 + rr) * APB + ks * 32 + kh * 8);
#pragma unroll
            for (int n = 0; n < 4; ++n)
                bfr[n] = *reinterpret_cast<const bf16x8*>(Bc + (wn * 64 + n * 16 + rr) * APB + ks * 32 + kh * 8);
#pragma unroll
            for (int m = 0; m < 4; ++m)
#pragma unroll
                for (int n = 0; n < 4; ++n)
                    oacc[m][n] = __builtin_amdgcn_mfma_f32_16x16x32_bf16(af[m], bfr[n], oacc[m][n], 0, 0, 0);
        }
#pragma unroll
        for (int m = 0; m < 4; ++m)
#pragma unroll
            for (int n = 0; n < 4; ++n) {
                const int u = uc0 + wn * 64 + n * 16 + rr;
#pragma unroll
                for (int reg = 0; reg < 4; ++reg) {
                    const int q = wm * 64 + m * 16 + kh * 4 + reg;
                    yo[((size_t)b * NT + q) * 1024 + 512 + u] = f2bf(oacc[m][n][reg]);
                }
            }
    }
}

// ---------------------------------------------------------------------------
// Both emb tables fp32 -> bf16, one launch.
// ---------------------------------------------------------------------------
__global__ __launch_bounds__(256)
void conv_emb2(const float* __restrict__ e0, const float* __restrict__ e1,
               unsigned short* __restrict__ o0, unsigned short* __restrict__ o1,
               int n, int nbh)
{
    int b = blockIdx.x;
    const float* e = e0; unsigned short* o = o0;
    if (b >= nbh) { b -= nbh; e = e1; o = o1; }
    const int i = (b * 256 + threadIdx.x) * 8;
    if (i >= n) return;
    const float4 v0 = reinterpret_cast<const float4*>(e + i)[0];
    const float4 v1 = reinterpret_cast<const float4*>(e + i)[1];
    u16x8 r;
    r[0] = f2bf(v0.x); r[1] = f2bf(v0.y); r[2] = f2bf(v0.z); r[3] = f2bf(v0.w);
    r[4] = f2bf(v1.x); r[5] = f2bf(v1.y); r[6] = f2bf(v1.z); r[7] = f2bf(v1.w);
    *reinterpret_cast<u16x8*>(o + i) = r;
}

// ---------------------------------------------------------------------------
// WhT[c][k] = bf16( k<512 ? Wh[k][c] : Wx[k-512][c] ); z selects enc/dec.
// ---------------------------------------------------------------------------
__global__ __launch_bounds__(256)
void conv_WhT2(const float* __restrict__ Wh_e, const float* __restrict__ Wx_e,
               const float* __restrict__ Wh_d, const float* __restrict__ Wx_d,
               unsigned short* __restrict__ WhT_e, unsigned short* __restrict__ WhT_d)
{
    __shared__ float lt[64][65];
    const float* Wh = (blockIdx.z == 0) ? Wh_e : Wh_d;
    const float* Wx = (blockIdx.z == 0) ? Wx_e : Wx_d;
    unsigned short* WhT = (blockIdx.z == 0) ? WhT_e : WhT_d;
    const int tid = threadIdx.x;
    const int c0 = blockIdx.x * 64;
    const int k0 = blockIdx.y * 64;
#pragma unroll
    for (int j = 0; j < 16; ++j) {
        const int lin = tid + 256 * j;
        const int kk = lin >> 6, cc = lin & 63;
        const int k = k0 + kk;
        lt[cc][kk] = (k < 512) ? Wh[(size_t)k * NG + c0 + cc]
                               : Wx[(size_t)(k - 512) * NG + c0 + cc];
    }
    __syncthreads();
    const int c = tid >> 2, kseg = tid & 3;
    unsigned short tmp[16];
#pragma unroll
    for (int m = 0; m < 16; ++m)
        tmp[m] = f2bf(lt[c][kseg * 16 + m]);
    unsigned short* dst = WhT + (size_t)(c0 + c) * KTOT + k0 + kseg * 16;
    *reinterpret_cast<u16x8*>(dst)     = *reinterpret_cast<u16x8*>(tmp);
    *reinterpret_cast<u16x8*>(dst + 8) = *reinterpret_cast<u16x8*>(tmp + 8);
}

// ---------------------------------------------------------------------------
// Transpose dense_W [1024][2000] fp32 -> Wt [2048][1024] bf16 (pad rows zero)
// ---------------------------------------------------------------------------
__global__ __launch_bounds__(256)
void conv_Wt(const float* __restrict__ W, unsigned short* __restrict__ Wt)
{
    __shared__ float lt[64][65];
    const int tid = threadIdx.x;
    const int c0 = blockIdx.x * 64;
    const int k0 = blockIdx.y * 64;
#pragma unroll
    for (int j = 0; j < 16; ++j) {
        const int lin = tid + 256 * j;
        const int kk = lin >> 6, cc = lin & 63;
        const int c = c0 + cc;
        lt[cc][kk] = (c < NV) ? W[(size_t)(k0 + kk) * NV + c] : 0.f;
    }
    __syncthreads();
    const int c = tid >> 2, kseg = tid & 3;
    unsigned short tmp[16];
#pragma unroll
    for (int m = 0; m < 16; ++m)
        tmp[m] = f2bf(lt[c][kseg * 16 + m]);
    unsigned short* dst = Wt + (size_t)(c0 + c) * 1024 + k0 + kseg * 16;
    *reinterpret_cast<u16x8*>(dst)     = *reinterpret_cast<u16x8*>(tmp);
    *reinterpret_cast<u16x8*>(dst + 8) = *reinterpret_cast<u16x8*>(tmp + 8);
}

// ---------------------------------------------------------------------------
// Dense via bf16 MFMA (R10 proven): out = yo[8192][1024] x Wt + b.
// ---------------------------------------------------------------------------
__global__ __launch_bounds__(256)
void dense_mfma(const unsigned short* __restrict__ yo,
                const unsigned short* __restrict__ Wt,
                const float* __restrict__ bias, float* __restrict__ out)
{
    __shared__ unsigned short Asm[128][40];
    __shared__ unsigned short Bsm[128][40];
    const int tid  = threadIdx.x;
    const int wave = tid >> 6, lane = tid & 63;
    const int wm = wave >> 1, wn = wave & 1;
    const int r0 = blockIdx.y * 128, c0 = blockIdx.x * 128;
    const int rr = lane & 15, kh = lane >> 4;

    f32x4 acc[4][4];
#pragma unroll
    for (int m = 0; m < 4; ++m)
#pragma unroll
        for (int n = 0; n < 4; ++n) acc[m][n] = (f32x4){0.f, 0.f, 0.f, 0.f};

    for (int k0 = 0; k0 < 1024; k0 += 32) {
        __syncthreads();
#pragma unroll
        for (int h = 0; h < 2; ++h) {
            const int row = (tid >> 2) + h * 64, seg = tid & 3;
            *reinterpret_cast<uint4*>(&Asm[row][seg * 8]) =
                *reinterpret_cast<const uint4*>(yo + (size_t)(r0 + row) * 1024 + k0 + seg * 8);
            *reinterpret_cast<uint4*>(&Bsm[row][seg * 8]) =
                *reinterpret_cast<const uint4*>(Wt + (size_t)(c0 + row) * 1024 + k0 + seg * 8);
        }
        __syncthreads();
        bf16x8 af[4], bfr[4];
#pragma unroll
        for (int m = 0; m < 4; ++m)
            af[m] = *reinterpret_cast<const bf16x8*>(&Asm[wm * 64 + m * 16 + rr][kh * 8]);
#pragma unroll
        for (int n = 0; n < 4; ++n)
            bfr[n] = *reinterpret_cast<const bf16x8*>(&Bsm[wn * 64 + n * 16 + rr][kh * 8]);
#pragma unroll
        for (int m = 0; m < 4; ++m)
#pragma unroll
            for (int n = 0; n < 4; ++n)
                acc[m][n] = __builtin_amdgcn_mfma_f32_16x16x32_bf16(af[m], bfr[n], acc[m][n], 0, 0, 0);
    }

#pragma unroll
    for (int m = 0; m < 4; ++m) {
#pragma unroll
        for (int n = 0; n < 4; ++n) {
            const int c = c0 + wn * 64 + n * 16 + rr;
            if (c < NV) {
                const float bc = bias[c];
#pragma unroll
                for (int reg = 0; reg < 4; ++reg) {
                    const int r = r0 + wm * 64 + m * 16 + kh * 4 + reg;
                    out[(size_t)r * NV + c] = acc[m][n][reg] + bc;
                }
            }
        }
    }
}

// ---------------------------------------------------------------------------
// In-place row softmax over V=2000 logits.
// ---------------------------------------------------------------------------
__global__ __launch_bounds__(256)
void softmax_rows(float* __restrict__ out)
{
    __shared__ float red[4];
    const int t = threadIdx.x;
    float* row = out + (size_t)blockIdx.x * NV;

    float v[8];
    float m = -INFINITY;
#pragma unroll
    for (int i = 0; i < 8; ++i) {
        const int j = t + 256 * i;
        v[i] = (j < NV) ? row[j] : -INFINITY;
        m = fmaxf(m, v[i]);
    }
#pragma unroll
    for (int o = 32; o; o >>= 1) m = fmaxf(m, __shfl_xor(m, o));
    if ((t & 63) == 0) red[t >> 6] = m;
    __syncthreads();
    m = fmaxf(fmaxf(red[0], red[1]), fmaxf(red[2], red[3]));
    __syncthreads();

    float s = 0.f;
#pragma unroll
    for (int i = 0; i < 8; ++i) {
        const int j = t + 256 * i;
        if (j < NV) { v[i] = expf(v[i] - m); s += v[i]; }
    }
#pragma unroll
    for (int o = 32; o; o >>= 1) s += __shfl_xor(s, o);
    if ((t & 63) == 0) red[t >> 6] = s;
    __syncthreads();
    const float inv = 1.f / (red[0] + red[1] + red[2] + red[3]);
#pragma unroll
    for (int i = 0; i < 8; ++i) {
        const int j = t + 256 * i;
        if (j < NV) row[j] = v[i] * inv;
    }
}

// ---------------------------------------------------------------------------
extern "C" void kernel_launch(void* const* d_in, const int* in_sizes, int n_in,
                              void* d_out, int out_size, void* d_ws, size_t ws_size,
                              hipStream_t stream)
{
    const int*   x       = (const int*)  d_in[0];
    const int*   y       = (const int*)  d_in[1];
    const float* enc_emb = (const float*)d_in[2];
    const float* enc_Wx  = (const float*)d_in[3];
    const float* enc_Wh  = (const float*)d_in[4];
    const float* enc_b   = (const float*)d_in[5];
    const float* dec_emb = (const float*)d_in[6];
    const float* dec_Wx  = (const float*)d_in[7];
    const float* dec_Wh  = (const float*)d_in[8];
    const float* dec_b   = (const float*)d_in[9];
    const float* dns_W   = (const float*)d_in[10];
    const float* dns_b   = (const float*)d_in[11];
    float* out = (float*)d_out;

    float* ws   = (float*)d_ws;
    float* Hbuf = ws;                                  // [B,T,U] fp32
    float* Sbuf = Hbuf + (size_t)NB * NT * NU;
    unsigned short* yo = (unsigned short*)(Sbuf + (size_t)NB * NT * NU);  // [8192][1024] bf16
    unsigned short* Wt = yo + (size_t)NB * NT * 1024;  // [2048][1024] bf16
    float* hping = (float*)(Wt + (size_t)2048 * 1024); // [2][B,U]
    float* hfin  = hping + 2 * BU;                     // enc final h
    unsigned int* bar0 = (unsigned int*)(hfin + BU);   // 512 flags (monotone 1..255)
    unsigned short* WhT_e = (unsigned short*)(bar0 + 512);
    unsigned short* WhT_d = WhT_e + (size_t)2048 * KTOT;
    unsigned short* embb_e = WhT_d + (size_t)2048 * KTOT;
    unsigned short* embb_d = embb_e + (size_t)NV * NE;

    // flags MUST be zeroed every call (0xAA poison would forge future values)
    hipMemsetAsync(bar0, 0, 512 * sizeof(unsigned int), stream);

    (void)hipFuncSetAttribute(reinterpret_cast<const void*>(lstm2_coop),
                              hipFuncAttributeMaxDynamicSharedMemorySize, SMEM_BYTES);
    (void)hipFuncSetAttribute(reinterpret_cast<const void*>(attn_mfma),
                              hipFuncAttributeMaxDynamicSharedMemorySize, SMEM_ATT);

    // one-time conversions
    const int nemb = NV * NE, nbh = (nemb / 8 + 255) / 256;
    conv_emb2<<<dim3(2 * nbh), dim3(256), 0, stream>>>(enc_emb, dec_emb, embb_e, embb_d, nemb, nbh);
    conv_WhT2<<<dim3(32, 9, 2), dim3(256), 0, stream>>>(enc_Wh, enc_Wx, dec_Wh, dec_Wx, WhT_e, WhT_d);
    conv_Wt<<<dim3(32, 16), dim3(256), 0, stream>>>(dns_W, Wt);

    {   // fused encoder+decoder LSTM
        void* args[] = { (void*)&x, (void*)&y, (void*)&embb_e, (void*)&embb_d,
                         (void*)&WhT_e, (void*)&WhT_d, (void*)&enc_b, (void*)&dec_b,
                         (void*)&Hbuf, (void*)&Sbuf, (void*)&hping, (void*)&hfin,
                         (void*)&yo, (void*)&bar0 };
        (void)hipLaunchCooperativeKernel(reinterpret_cast<void*>(lstm2_coop),
                                         dim3(GRID_LSTM), dim3(512), args,
                                         SMEM_BYTES, stream);
    }
    attn_mfma<<<dim3(NB), dim3(256), SMEM_ATT, stream>>>(Sbuf, Hbuf, hfin, yo);
    dense_mfma<<<dim3(16, 64), dim3(256), 0, stream>>>(yo, Wt, dns_b, out);
    softmax_rows<<<dim3(NB * NT), dim3(256), 0, stream>>>(out);
}

// Round 13
// 863.906 us; speedup vs baseline: 2.8663x; 1.0195x over previous
//
#include <hip/hip_runtime.h>
#include <math.h>

#define NB 64       // batch
#define NT 128      // time steps
#define NE 64       // embedding
#define NU 512      // units
#define NG 2048     // 4*U
#define NV 2000     // vocab
#define BU (NB*NU)
#define GRID_LSTM 256
#define KTOT 576        // 512 (h) + 64 (emb) = 18 K-tiles of 32
#define HS 584          // hlds row stride (shorts)
#define WSTRIDE 584     // whb row stride (shorts)
#define SMEM_BYTES (64*WSTRIDE*2 + 16*HS*2 + 2*8*64*4)   // 97536

// attn_mfma dynamic LDS layout (bytes) — 64-q-row blocks
#define ASSC 129        // scores stride (f32)
#define APB  136        // P / B-chunk stride (bf16)
#define OFF_SSC 0                       // [64][129] f32 (33024) / Bc [128][136] bf16 (34816)
#define OFF_PB  34816                   // [64][136] bf16 (17408)
#define OFF_ASM 52224                   // [64][40] bf16  (5120)
#define OFF_BSM 57344                   // [128][40] bf16 (10240)
#define SMEM_ATT 67584

typedef __attribute__((ext_vector_type(8))) short bf16x8;
typedef __attribute__((ext_vector_type(4))) float f32x4;
typedef __attribute__((ext_vector_type(8))) unsigned short u16x8;

__device__ __forceinline__ unsigned short f2bf(float x) {
    unsigned int u = __float_as_uint(x);
    u += 0x7FFFu + ((u >> 16) & 1u);
    return (unsigned short)(u >> 16);
}
__device__ __forceinline__ float fsigmoid(float x) {
    return __builtin_amdgcn_rcpf(1.f + __expf(-x));
}
__device__ __forceinline__ float ftanh(float x) {
    return 1.f - 2.f * __builtin_amdgcn_rcpf(__expf(2.f * x) + 1.f);
}

// ---------------------------------------------------------------------------
// Fused encoder+decoder cooperative LSTM (R11/R12, PROVEN — byte-identical).
// ---------------------------------------------------------------------------
__global__ __launch_bounds__(512, 1)
void lstm2_coop(const int* __restrict__ xids, const int* __restrict__ yids,
                const unsigned short* __restrict__ embb_e,
                const unsigned short* __restrict__ embb_d,
                const unsigned short* __restrict__ WhT_e,
                const unsigned short* __restrict__ WhT_d,
                const float* __restrict__ enc_b, const float* __restrict__ dec_b,
                float* __restrict__ Hbuf, float* __restrict__ Sbuf,
                float* __restrict__ hping, float* __restrict__ hfin,
                unsigned short* __restrict__ yo,
                unsigned int* __restrict__ flags)
{
    extern __shared__ char smem[];
    unsigned short* whb  = (unsigned short*)smem;                      // [64][WSTRIDE]
    unsigned short* hlds = (unsigned short*)(smem + 64 * WSTRIDE * 2); // [16][HS] bf16
    float* zbuf = (float*)(smem + 64 * WSTRIDE * 2 + 16 * HS * 2);     // [2][8][64]

    const int tid  = threadIdx.x;
    const int wv   = tid >> 6;
    const int cl   = tid & 63;
    const int bk   = blockIdx.x;
    const int rg   = bk & 7;                   // group (8 groups x 32 blocks)
    const int cgi  = bk >> 3;                  // 0..31 unit slice
    const int brow0 = rg * 8;
    const int u0    = cgi * 16;

    const int bl  = tid >> 4;                  // tid<128: row
    const int uug = tid & 15;
    float creg = 0.f;
    float b4[4] = {0.f, 0.f, 0.f, 0.f};
    if (tid < 128) {
#pragma unroll
        for (int g = 0; g < 4; ++g) b4[g] = enc_b[g * 512 + u0 + uug];
    }

    // ---- stage B (enc WhT slice -> LDS): col cp, k-chunk ch (72 shorts)
    {
        const int cp = tid >> 3, ch = tid & 7;
        const int cg = (cp >> 4) * 512 + u0 + (cp & 15);
        const uint4* src = reinterpret_cast<const uint4*>(WhT_e + (size_t)cg * KTOT + ch * 72);
        uint4* dst = reinterpret_cast<uint4*>(whb + cp * WSTRIDE + ch * 72);
#pragma unroll
        for (int i = 0; i < 9; ++i) dst[i] = src[i];
    }

    // ---- h(0)=0 bf16, zero pad rows 8-15, stage emb(0) from x
    const int col = wv * 64 + cl;
#pragma unroll
    for (int b = 0; b < 8; ++b) hlds[b * HS + col] = 0;
    for (int i = tid; i < 8 * HS; i += 512) hlds[8 * HS + i] = 0;
    {
        const int idb = xids[(brow0 + wv) * NT + 0];
        hlds[wv * HS + 512 + cl] = embb_e[(size_t)idb * NE + cl];
    }
    unsigned int* fl = flags + rg * 64;

    for (int T = 0; T < 2 * NT; ++T) {
        const int t = T & (NT - 1);
        float* Ho = (T < NT) ? Hbuf : Sbuf;
        __syncthreads();                       // B#0: hlds + whb visible

        // ---- z = [h|emb] @ W via MFMA: wave = (gate wv&3, K-half wv>>2)
        {
            const int g = wv & 3, half = wv >> 2;
            const int rr = cl & 15, kh = cl >> 4;
            f32x4 acc = {0.f, 0.f, 0.f, 0.f};
            const unsigned short* arow = hlds + rr * HS;
            const unsigned short* brow = whb + (g * 16 + rr) * WSTRIDE;
#pragma unroll
            for (int kt = 0; kt < 9; ++kt) {
                const int kb = (half * 9 + kt) * 32 + kh * 8;
                bf16x8 af = *reinterpret_cast<const bf16x8*>(arow + kb);
                bf16x8 bf = *reinterpret_cast<const bf16x8*>(brow + kb);
                acc = __builtin_amdgcn_mfma_f32_16x16x32_bf16(af, bf, acc, 0, 0, 0);
            }
            if (cl < 32) {
#pragma unroll
                for (int reg = 0; reg < 4; ++reg)
                    zbuf[half * 512 + (kh * 4 + reg) * 64 + g * 16 + rr] = acc[reg];
            }
        }
        __syncthreads();                       // B#1: zbuf complete

        // ---- gates + state update + h publish (EXACT proven protocol)
        float h_ = 0.f;
        if (tid < 128) {
            float z[4];
#pragma unroll
            for (int g = 0; g < 4; ++g)
                z[g] = b4[g] + zbuf[bl * 64 + g * 16 + uug]
                             + zbuf[512 + bl * 64 + g * 16 + uug];
            const float i_ = fsigmoid(z[0]);
            const float f_ = fsigmoid(z[1]);
            const float g_ = ftanh(z[2]);
            const float o_ = fsigmoid(z[3]);
            creg = f_ * creg + i_ * g_;
            h_ = o_ * ftanh(creg);
            float* hw = hping + ((T + 1) & 1) * BU;
            __hip_atomic_store(&hw[(brow0 + bl) * NU + u0 + uug], h_,
                               __ATOMIC_RELAXED, __HIP_MEMORY_SCOPE_AGENT);
        }
        if (T == 2 * NT - 1) {
            if (tid < 128) {
                const size_t r = (size_t)(brow0 + bl) * NT + t;
                Ho[r * NU + u0 + uug] = h_;
                yo[r * 1024 + u0 + uug] = f2bf(h_);
            }
            break;                             // flushed at kernel end
        }

        if (tid < 128)
            asm volatile("s_waitcnt vmcnt(0)" ::: "memory");  // h at coherence pt
        __syncthreads();                       // B#2: all h stores complete

        if (tid < 128 && (tid & 63) == 0)
            __hip_atomic_store(&fl[(tid >> 6) * 32 + cgi], (unsigned)(T + 1),
                               __ATOMIC_RELAXED, __HIP_MEMORY_SCOPE_AGENT);
        if (tid < 128) {                       // off critical path: drain in bg
            const size_t r = (size_t)(brow0 + bl) * NT + t;
            Ho[r * NU + u0 + uug] = h_;
            if (T >= NT) yo[r * 1024 + u0 + uug] = f2bf(h_);
            if (T == NT - 1)                   // enc final h for attention s0
                hfin[(brow0 + bl) * NU + u0 + uug] = h_;
        }

        // ---- stage emb(T+1) (independent of h(T+1): hides in poll window)
        {
            const int Tn = T + 1;
            const int* nids = (Tn < NT) ? xids : yids;
            const unsigned short* nemb = (Tn < NT) ? embb_e : embb_d;
            const int idb = nids[(brow0 + wv) * NT + (Tn & (NT - 1))];
            hlds[wv * HS + 512 + cl] = nemb[(size_t)idb * NE + cl];
        }

        if (wv == 0) {                         // single polling wave per block
            const unsigned target = (unsigned)(T + 1);
            while (true) {
                unsigned v = __hip_atomic_load(&fl[cl], __ATOMIC_RELAXED,
                                               __HIP_MEMORY_SCOPE_AGENT);
#pragma unroll
                for (int o = 16; o; o >>= 1) {
                    unsigned v2 = (unsigned)__shfl_xor((int)v, o);
                    v = v2 < v ? v2 : v;
                }
                if (v >= target) break;
                __builtin_amdgcn_s_sleep(1);
            }
        }
        __syncthreads();                       // B#3: release all waves

        // ---- reload own h slice fp32 -> bf16 into LDS
        {
            const float* hr = hping + ((T + 1) & 1) * BU + (size_t)brow0 * NU;
            float tmp[8];
#pragma unroll
            for (int b = 0; b < 8; ++b)
                tmp[b] = __hip_atomic_load(const_cast<float*>(&hr[b * NU + col]),
                                           __ATOMIC_RELAXED, __HIP_MEMORY_SCOPE_AGENT);
#pragma unroll
            for (int b = 0; b < 8; ++b) hlds[b * HS + col] = f2bf(tmp[b]);
        }

        // ---- enc->dec boundary: restage whb from dec weights, switch bias
        if (T == NT - 1) {
            const int cp = tid >> 3, ch = tid & 7;
            const int cg = (cp >> 4) * 512 + u0 + (cp & 15);
            const uint4* src = reinterpret_cast<const uint4*>(WhT_d + (size_t)cg * KTOT + ch * 72);
            uint4* dst = reinterpret_cast<uint4*>(whb + cp * WSTRIDE + ch * 72);
#pragma unroll
            for (int i = 0; i < 9; ++i) dst[i] = src[i];
            if (tid < 128) {
#pragma unroll
                for (int g = 0; g < 4; ++g) b4[g] = dec_b[g * 512 + u0 + uug];
            }
        }
    }
}

// ---------------------------------------------------------------------------
// MFMA attention, 2 blocks per batch: bk = (b<<1)|qh, each handles 64 q-rows.
// Phase 1: scores (64q x 128k, K=512). Phase 2: row softmax (64 rows).
// Phase 3: A = P @ H (64q x 512u, K=128). Per-row math identical to R12.
// ---------------------------------------------------------------------------
__global__ __launch_bounds__(256)
void attn_mfma(const float* __restrict__ S, const float* __restrict__ Hbuf,
               const float* __restrict__ s0, unsigned short* __restrict__ yo)
{
    extern __shared__ char smem[];
    float* Ssc = (float*)(smem + OFF_SSC);                    // [64][129] f32
    unsigned short* Bc  = (unsigned short*)(smem + OFF_SSC);  // later: [128][136] bf16
    unsigned short* Pb  = (unsigned short*)(smem + OFF_PB);   // [64][136] bf16
    unsigned short* Asm_ = (unsigned short*)(smem + OFF_ASM); // [64][40]
    unsigned short* Bsm_ = (unsigned short*)(smem + OFF_BSM); // [128][40]

    const int tid  = threadIdx.x;
    const int wave = tid >> 6, lane = tid & 63;
    const int wm = wave >> 1, wn = wave & 1;
    const int rr = lane & 15, kh = lane >> 4;
    const int b  = blockIdx.x >> 1;
    const int qh = blockIdx.x & 1;
    const float* Hb = Hbuf + (size_t)b * NT * NU;

    // ================= Phase 1: scores = S_ @ H^T =================
    f32x4 acc[2][4];
#pragma unroll
    for (int m = 0; m < 2; ++m)
#pragma unroll
        for (int n = 0; n < 4; ++n) acc[m][n] = (f32x4){0.f, 0.f, 0.f, 0.f};

    for (int k0 = 0; k0 < 512; k0 += 32) {
        __syncthreads();
        {   // A: 64 q-rows, one pass
            const int row = tid >> 2, seg = tid & 3;
            const int q = qh * 64 + row;
            const float* qsrc = (q == 0) ? (s0 + (size_t)b * NU)
                                         : (S + ((size_t)b * NT + q - 1) * NU);
            const float4 a0 = reinterpret_cast<const float4*>(qsrc + k0 + seg * 8)[0];
            const float4 a1 = reinterpret_cast<const float4*>(qsrc + k0 + seg * 8)[1];
            u16x8 av;
            av[0] = f2bf(a0.x); av[1] = f2bf(a0.y); av[2] = f2bf(a0.z); av[3] = f2bf(a0.w);
            av[4] = f2bf(a1.x); av[5] = f2bf(a1.y); av[6] = f2bf(a1.z); av[7] = f2bf(a1.w);
            *reinterpret_cast<u16x8*>(Asm_ + row * 40 + seg * 8) = av;
        }
#pragma unroll
        for (int h = 0; h < 2; ++h) {          // B: 128 k-rows, two passes
            const int row = (tid >> 2) + h * 64, seg = tid & 3;
            const float4 b0 = reinterpret_cast<const float4*>(Hb + (size_t)row * NU + k0 + seg * 8)[0];
            const float4 b1 = reinterpret_cast<const float4*>(Hb + (size_t)row * NU + k0 + seg * 8)[1];
            u16x8 bv;
            bv[0] = f2bf(b0.x); bv[1] = f2bf(b0.y); bv[2] = f2bf(b0.z); bv[3] = f2bf(b0.w);
            bv[4] = f2bf(b1.x); bv[5] = f2bf(b1.y); bv[6] = f2bf(b1.z); bv[7] = f2bf(b1.w);
            *reinterpret_cast<u16x8*>(Bsm_ + row * 40 + seg * 8) = bv;
        }
        __syncthreads();
        bf16x8 af[2], bfr[4];
#pragma unroll
        for (int m = 0; m < 2; ++m)
            af[m] = *reinterpret_cast<const bf16x8*>(Asm_ + (wm * 32 + m * 16 + rr) * 40 + kh * 8);
#pragma unroll
        for (int n = 0; n < 4; ++n)
            bfr[n] = *reinterpret_cast<const bf16x8*>(Bsm_ + (wn * 64 + n * 16 + rr) * 40 + kh * 8);
#pragma unroll
        for (int m = 0; m < 2; ++m)
#pragma unroll
            for (int n = 0; n < 4; ++n)
                acc[m][n] = __builtin_amdgcn_mfma_f32_16x16x32_bf16(af[m], bfr[n], acc[m][n], 0, 0, 0);
    }
    __syncthreads();
#pragma unroll
    for (int m = 0; m < 2; ++m)
#pragma unroll
        for (int n = 0; n < 4; ++n)
#pragma unroll
            for (int reg = 0; reg < 4; ++reg)
                Ssc[(wm * 32 + m * 16 + kh * 4 + reg) * ASSC + wn * 64 + n * 16 + rr] = acc[m][n][reg];
    __syncthreads();

    // ================= Phase 2: row softmax -> Pb (bf16) =================
    if (tid < 128) {
        const int row = tid >> 1, half = tid & 1;
        float* srow = Ssc + row * ASSC + half * 64;
        float mx = -INFINITY;
#pragma unroll 8
        for (int j = 0; j < 64; ++j) mx = fmaxf(mx, srow[j]);
        mx = fmaxf(mx, __shfl_xor(mx, 1));
        float sum = 0.f;
#pragma unroll 8
        for (int j = 0; j < 64; ++j) { float e = __expf(srow[j] - mx); srow[j] = e; sum += e; }
        sum += __shfl_xor(sum, 1);
        const float inv = 1.f / sum;
#pragma unroll 8
        for (int j = 0; j < 64; ++j)
            Pb[row * APB + half * 64 + j] = f2bf(srow[j] * inv);
    }

    // ================= Phase 3: A = P @ H, output bf16 =================
    for (int nc = 0; nc < 4; ++nc) {
        const int uc0 = nc * 128;
        __syncthreads();                   // Ssc reads done / prev Bc reads done
        // stage H-chunk transposed: Bc[u][k], u 0..127, k 0..127
#pragma unroll
        for (int c4 = 0; c4 < 4; ++c4) {
            const int kk = (tid >> 3) + 32 * c4;
            const int u0t = (tid & 7) * 16;
            const float* hsrc = Hb + (size_t)kk * NU + uc0 + u0t;
#pragma unroll
            for (int q4 = 0; q4 < 4; ++q4) {
                const float4 v = reinterpret_cast<const float4*>(hsrc)[q4];
                Bc[(u0t + q4 * 4 + 0) * APB + kk] = f2bf(v.x);
                Bc[(u0t + q4 * 4 + 1) * APB + kk] = f2bf(v.y);
                Bc[(u0t + q4 * 4 + 2) * APB + kk] = f2bf(v.z);
                Bc[(u0t + q4 * 4 + 3) * APB + kk] = f2bf(v.w);
            }
        }
        __syncthreads();

        f32x4 oacc[2][4];
#pragma unroll
        for (int m = 0; m < 2; ++m)
#pragma unroll
            for (int n = 0; n < 4; ++n) oacc[m][n] = (f32x4){0.f, 0.f, 0.f, 0.f};
#pragma unroll
        for (int ks = 0; ks < 4; ++ks) {
            bf16x8 af[2], bfr[4];
#pragma unroll
            for (int m = 0; m < 2; ++m)
                af[m] = *reinterpret_cast<const bf16x8*>(Pb + (wm * 32 + m * 16 + rr) * APB + ks * 32 + kh * 8);
#pragma unroll
            for (int n = 0; n < 4; ++n)
                bfr[n] = *reinterpret_cast<const bf16x8*>(Bc + (wn * 64 + n * 16 + rr) * APB + ks * 32 + kh * 8);
#pragma unroll
            for (int m = 0; m < 2; ++m)
#pragma unroll
                for (int n = 0; n < 4; ++n)
                    oacc[m][n] = __builtin_amdgcn_mfma_f32_16x16x32_bf16(af[m], bfr[n], oacc[m][n], 0, 0, 0);
        }
#pragma unroll
        for (int m = 0; m < 2; ++m)
#pragma unroll
            for (int n = 0; n < 4; ++n) {
                const int u = uc0 + wn * 64 + n * 16 + rr;
#pragma unroll
                for (int reg = 0; reg < 4; ++reg) {
                    const int q = qh * 64 + wm * 32 + m * 16 + kh * 4 + reg;
                    yo[((size_t)b * NT + q) * 1024 + 512 + u] = f2bf(oacc[m][n][reg]);
                }
            }
    }
}

// ---------------------------------------------------------------------------
// All one-time conversions in ONE launch. Block ranges:
//   [0, 2*nbh)            : emb tables fp32->bf16 (enc then dec)
//   [2*nbh, 2*nbh+576)    : WhT enc/dec (32 c-tiles x 9 k-tiles x 2)
//   [2*nbh+576, +512)     : Wt (32 c-tiles x 16 k-tiles)
// ---------------------------------------------------------------------------
__global__ __launch_bounds__(256)
void conv_all(const float* __restrict__ enc_emb, const float* __restrict__ dec_emb,
              const float* __restrict__ Wh_e, const float* __restrict__ Wx_e,
              const float* __restrict__ Wh_d, const float* __restrict__ Wx_d,
              const float* __restrict__ dns_W,
              unsigned short* __restrict__ embb_e, unsigned short* __restrict__ embb_d,
              unsigned short* __restrict__ WhT_e, unsigned short* __restrict__ WhT_d,
              unsigned short* __restrict__ Wt, int nbh)
{
    __shared__ float lt[64][65];
    const int tid = threadIdx.x;
    int blk = blockIdx.x;

    if (blk < 2 * nbh) {                       // ---- emb conversion
        const float* e = (blk < nbh) ? enc_emb : dec_emb;
        unsigned short* o = (blk < nbh) ? embb_e : embb_d;
        const int bb = (blk < nbh) ? blk : blk - nbh;
        const int i = (bb * 256 + tid) * 8;
        if (i < NV * NE) {
            const float4 v0 = reinterpret_cast<const float4*>(e + i)[0];
            const float4 v1 = reinterpret_cast<const float4*>(e + i)[1];
            u16x8 r;
            r[0] = f2bf(v0.x); r[1] = f2bf(v0.y); r[2] = f2bf(v0.z); r[3] = f2bf(v0.w);
            r[4] = f2bf(v1.x); r[5] = f2bf(v1.y); r[6] = f2bf(v1.z); r[7] = f2bf(v1.w);
            *reinterpret_cast<u16x8*>(o + i) = r;
        }
        return;
    }
    blk -= 2 * nbh;

    if (blk < 576) {                           // ---- WhT enc/dec
        const int z  = blk / 288;
        const int rem = blk - z * 288;
        const int ky = rem >> 5, cx = rem & 31;
        const float* Wh = z ? Wh_d : Wh_e;
        const float* Wx = z ? Wx_d : Wx_e;
        unsigned short* WhT = z ? WhT_d : WhT_e;
        const int c0 = cx * 64, k0 = ky * 64;
#pragma unroll
        for (int j = 0; j < 16; ++j) {
            const int lin = tid + 256 * j;
            const int kk = lin >> 6, cc = lin & 63;
            const int k = k0 + kk;
            lt[cc][kk] = (k < 512) ? Wh[(size_t)k * NG + c0 + cc]
                                   : Wx[(size_t)(k - 512) * NG + c0 + cc];
        }
        __syncthreads();
        const int c = tid >> 2, kseg = tid & 3;
        unsigned short tmp[16];
#pragma unroll
        for (int m = 0; m < 16; ++m) tmp[m] = f2bf(lt[c][kseg * 16 + m]);
        unsigned short* dst = WhT + (size_t)(c0 + c) * KTOT + k0 + kseg * 16;
        *reinterpret_cast<u16x8*>(dst)     = *reinterpret_cast<u16x8*>(tmp);
        *reinterpret_cast<u16x8*>(dst + 8) = *reinterpret_cast<u16x8*>(tmp + 8);
        return;
    }
    blk -= 576;

    {                                          // ---- Wt (dense weight)
        const int ky = blk >> 5, cx = blk & 31;
        const int c0 = cx * 64, k0 = ky * 64;
#pragma unroll
        for (int j = 0; j < 16; ++j) {
            const int lin = tid + 256 * j;
            const int kk = lin >> 6, cc = lin & 63;
            const int c = c0 + cc;
            lt[cc][kk] = (c < NV) ? dns_W[(size_t)(k0 + kk) * NV + c] : 0.f;
        }
        __syncthreads();
        const int c = tid >> 2, kseg = tid & 3;
        unsigned short tmp[16];
#pragma unroll
        for (int m = 0; m < 16; ++m) tmp[m] = f2bf(lt[c][kseg * 16 + m]);
        unsigned short* dst = Wt + (size_t)(c0 + c) * 1024 + k0 + kseg * 16;
        *reinterpret_cast<u16x8*>(dst)     = *reinterpret_cast<u16x8*>(tmp);
        *reinterpret_cast<u16x8*>(dst + 8) = *reinterpret_cast<u16x8*>(tmp + 8);
    }
}

// ---------------------------------------------------------------------------
// Dense via bf16 MFMA (R10 proven): out = yo[8192][1024] x Wt + b.
// ---------------------------------------------------------------------------
__global__ __launch_bounds__(256)
void dense_mfma(const unsigned short* __restrict__ yo,
                const unsigned short* __restrict__ Wt,
                const float* __restrict__ bias, float* __restrict__ out)
{
    __shared__ unsigned short Asm[128][40];
    __shared__ unsigned short Bsm[128][40];
    const int tid  = threadIdx.x;
    const int wave = tid >> 6, lane = tid & 63;
    const int wm = wave >> 1, wn = wave & 1;
    const int r0 = blockIdx.y * 128, c0 = blockIdx.x * 128;
    const int rr = lane & 15, kh = lane >> 4;

    f32x4 acc[4][4];
#pragma unroll
    for (int m = 0; m < 4; ++m)
#pragma unroll
        for (int n = 0; n < 4; ++n) acc[m][n] = (f32x4){0.f, 0.f, 0.f, 0.f};

    for (int k0 = 0; k0 < 1024; k0 += 32) {
        __syncthreads();
#pragma unroll
        for (int h = 0; h < 2; ++h) {
            const int row = (tid >> 2) + h * 64, seg = tid & 3;
            *reinterpret_cast<uint4*>(&Asm[row][seg * 8]) =
                *reinterpret_cast<const uint4*>(yo + (size_t)(r0 + row) * 1024 + k0 + seg * 8);
            *reinterpret_cast<uint4*>(&Bsm[row][seg * 8]) =
                *reinterpret_cast<const uint4*>(Wt + (size_t)(c0 + row) * 1024 + k0 + seg * 8);
        }
        __syncthreads();
        bf16x8 af[4], bfr[4];
#pragma unroll
        for (int m = 0; m < 4; ++m)
            af[m] = *reinterpret_cast<const bf16x8*>(&Asm[wm * 64 + m * 16 + rr][kh * 8]);
#pragma unroll
        for (int n = 0; n < 4; ++n)
            bfr[n] = *reinterpret_cast<const bf16x8*>(&Bsm[wn * 64 + n * 16 + rr][kh * 8]);
#pragma unroll
        for (int m = 0; m < 4; ++m)
#pragma unroll
            for (int n = 0; n < 4; ++n)
                acc[m][n] = __builtin_amdgcn_mfma_f32_16x16x32_bf16(af[m], bfr[n], acc[m][n], 0, 0, 0);
    }

#pragma unroll
    for (int m = 0; m < 4; ++m) {
#pragma unroll
        for (int n = 0; n < 4; ++n) {
            const int c = c0 + wn * 64 + n * 16 + rr;
            if (c < NV) {
                const float bc = bias[c];
#pragma unroll
                for (int reg = 0; reg < 4; ++reg) {
                    const int r = r0 + wm * 64 + m * 16 + kh * 4 + reg;
                    out[(size_t)r * NV + c] = acc[m][n][reg] + bc;
                }
            }
        }
    }
}

// ---------------------------------------------------------------------------
// In-place row softmax over V=2000 logits.
// ---------------------------------------------------------------------------
__global__ __launch_bounds__(256)
void softmax_rows(float* __restrict__ out)
{
    __shared__ float red[4];
    const int t = threadIdx.x;
    float* row = out + (size_t)blockIdx.x * NV;

    float v[8];
    float m = -INFINITY;
#pragma unroll
    for (int i = 0; i < 8; ++i) {
        const int j = t + 256 * i;
        v[i] = (j < NV) ? row[j] : -INFINITY;
        m = fmaxf(m, v[i]);
    }
#pragma unroll
    for (int o = 32; o; o >>= 1) m = fmaxf(m, __shfl_xor(m, o));
    if ((t & 63) == 0) red[t >> 6] = m;
    __syncthreads();
    m = fmaxf(fmaxf(red[0], red[1]), fmaxf(red[2], red[3]));
    __syncthreads();

    float s = 0.f;
#pragma unroll
    for (int i = 0; i < 8; ++i) {
        const int j = t + 256 * i;
        if (j < NV) { v[i] = expf(v[i] - m); s += v[i]; }
    }
#pragma unroll
    for (int o = 32; o; o >>= 1) s += __shfl_xor(s, o);
    if ((t & 63) == 0) red[t >> 6] = s;
    __syncthreads();
    const float inv = 1.f / (red[0] + red[1] + red[2] + red[3]);
#pragma unroll
    for (int i = 0; i < 8; ++i) {
        const int j = t + 256 * i;
        if (j < NV) row[j] = v[i] * inv;
    }
}

// ---------------------------------------------------------------------------
extern "C" void kernel_launch(void* const* d_in, const int* in_sizes, int n_in,
                              void* d_out, int out_size, void* d_ws, size_t ws_size,
                              hipStream_t stream)
{
    const int*   x       = (const int*)  d_in[0];
    const int*   y       = (const int*)  d_in[1];
    const float* enc_emb = (const float*)d_in[2];
    const float* enc_Wx  = (const float*)d_in[3];
    const float* enc_Wh  = (const float*)d_in[4];
    const float* enc_b   = (const float*)d_in[5];
    const float* dec_emb = (const float*)d_in[6];
    const float* dec_Wx  = (const float*)d_in[7];
    const float* dec_Wh  = (const float*)d_in[8];
    const float* dec_b   = (const float*)d_in[9];
    const float* dns_W   = (const float*)d_in[10];
    const float* dns_b   = (const float*)d_in[11];
    float* out = (float*)d_out;

    float* ws   = (float*)d_ws;
    float* Hbuf = ws;                                  // [B,T,U] fp32
    float* Sbuf = Hbuf + (size_t)NB * NT * NU;
    unsigned short* yo = (unsigned short*)(Sbuf + (size_t)NB * NT * NU);  // [8192][1024] bf16
    unsigned short* Wt = yo + (size_t)NB * NT * 1024;  // [2048][1024] bf16
    float* hping = (float*)(Wt + (size_t)2048 * 1024); // [2][B,U]
    float* hfin  = hping + 2 * BU;                     // enc final h
    unsigned int* bar0 = (unsigned int*)(hfin + BU);   // 512 flags (monotone 1..255)
    unsigned short* WhT_e = (unsigned short*)(bar0 + 512);
    unsigned short* WhT_d = WhT_e + (size_t)2048 * KTOT;
    unsigned short* embb_e = WhT_d + (size_t)2048 * KTOT;
    unsigned short* embb_d = embb_e + (size_t)NV * NE;

    // flags MUST be zeroed every call (0xAA poison would forge future values)
    hipMemsetAsync(bar0, 0, 512 * sizeof(unsigned int), stream);

    (void)hipFuncSetAttribute(reinterpret_cast<const void*>(lstm2_coop),
                              hipFuncAttributeMaxDynamicSharedMemorySize, SMEM_BYTES);
    (void)hipFuncSetAttribute(reinterpret_cast<const void*>(attn_mfma),
                              hipFuncAttributeMaxDynamicSharedMemorySize, SMEM_ATT);

    // all one-time conversions in one launch
    const int nemb = NV * NE, nbh = (nemb / 8 + 255) / 256;
    conv_all<<<dim3(2 * nbh + 576 + 512), dim3(256), 0, stream>>>(
        enc_emb, dec_emb, enc_Wh, enc_Wx, dec_Wh, dec_Wx, dns_W,
        embb_e, embb_d, WhT_e, WhT_d, Wt, nbh);

    {   // fused encoder+decoder LSTM
        void* args[] = { (void*)&x, (void*)&y, (void*)&embb_e, (void*)&embb_d,
                         (void*)&WhT_e, (void*)&WhT_d, (void*)&enc_b, (void*)&dec_b,
                         (void*)&Hbuf, (void*)&Sbuf, (void*)&hping, (void*)&hfin,
                         (void*)&yo, (void*)&bar0 };
        (void)hipLaunchCooperativeKernel(reinterpret_cast<void*>(lstm2_coop),
                                         dim3(GRID_LSTM), dim3(512), args,
                                         SMEM_BYTES, stream);
    }
    attn_mfma<<<dim3(NB * 2), dim3(256), SMEM_ATT, stream>>>(Sbuf, Hbuf, hfin, yo);
    dense_mfma<<<dim3(16, 64), dim3(256), 0, stream>>>(yo, Wt, dns_b, out);
    softmax_rows<<<dim3(NB * NT), dim3(256), 0, stream>>>(out);
}